// Round 19
// baseline (3073.624 us; speedup 1.0000x reference)
//
#include <hip/hip_runtime.h>
#include <hip/hip_bf16.h>
#include <math.h>

typedef unsigned short u16;
typedef unsigned int u32;
typedef _Float16 f16;
typedef __attribute__((ext_vector_type(8))) _Float16 f16x8;
typedef __attribute__((ext_vector_type(8))) short short8;
typedef __attribute__((ext_vector_type(4))) float f32x4;

#define TTOK 65536
#define QTOK 16384
#define CAP 13108
#define CAPP 13184  // 103*128

#define MFMA16(a, b, c) __builtin_amdgcn_mfma_f32_16x16x32_f16(a, b, c, 0, 0, 0)
#define MFMAB(a, b, c) __builtin_amdgcn_mfma_f32_16x16x32_bf16(a, b, c, 0, 0, 0)
#define LO_SCALE 2.44140625e-4f  // 2^-12

// 3-bit XOR swizzle: slot s of row r holds col-seg s ^ F(r).
#define SWZF(r) (((r) & 3) ^ ((((r) >> 2) & 1) << 1))

__device__ __forceinline__ u16 f2bf(float f) {
  union { float f; u32 u; } v; v.f = f;
  u32 r = v.u + 0x7fffu + ((v.u >> 16) & 1u);
  return (u16)(r >> 16);
}
__device__ __forceinline__ u16 f16b(f16 h) {
  union { f16 h; u16 u; } v; v.h = h; return v.u;
}
__device__ __forceinline__ f16 b2h(u16 u) {
  union { u16 s; f16 h; } v; v.s = u; return v.h;
}
// Fast exact GELU: A&S 7.1.26 erf, |err|<=1.5e-7 (far below bf16 noise).
__device__ __forceinline__ float gelu_f(float x) {
  float z = fabsf(x) * 0.70710678118654752f;
  float t = __builtin_amdgcn_rcpf(1.0f + 0.3275911f * z);
  float p = t * (0.254829592f + t * (-0.284496736f + t * (1.421413741f
          + t * (-1.453152027f + t * 1.061405429f))));
  float er = 1.0f - p * __expf(-z * z);
  er = (x < 0.0f) ? -er : er;
  return 0.5f * x * (1.0f + er);
}
// async global->LDS, 16B per lane; dest = wave-uniform base + lane*16
__device__ __forceinline__ void gl16(const u16* g, u16* l) {
  __builtin_amdgcn_global_load_lds(
      (const __attribute__((address_space(1))) u32*)(const void*)g,
      (__attribute__((address_space(3))) u32*)(void*)l, 16, 0, 0);
}

// ---------------------------------------------------------------------------
// prep1: wq/wk/wv/wo [K=512][N=512] f32 -> f16 hi/lo planes [2048][512];
// router_w -> rwt [8][512] f32.
__global__ __launch_bounds__(256) void prep1_kernel(
    const float* __restrict__ wq, const float* __restrict__ wk,
    const float* __restrict__ wv, const float* __restrict__ wo,
    const float* __restrict__ rw,
    u16* __restrict__ whi, u16* __restrict__ wlo, float* __restrict__ rwt)
{
  const int z = blockIdx.z;
  int idx = blockIdx.x * 256 + threadIdx.x;
  if (z == 4) {
    if (idx < 4096) {
      int n = idx >> 9, k = idx & 511;
      rwt[idx] = rw[k * 8 + n];
    }
    return;
  }
  const float* src = (z == 0) ? wq : (z == 1) ? wk : (z == 2) ? wv : wo;
  int n = idx >> 9, k = idx & 511;
  float v = src[k * 512 + n];
  f16 h = (f16)v;
  f16 l = (f16)((v - (float)h) * 4096.0f);
  whi[z * 262144 + idx] = f16b(h);
  wlo[z * 262144 + idx] = f16b(l);
}

// ---------------------------------------------------------------------------
// prep2: LDS-tiled transpose to bf16.
__global__ __launch_bounds__(256) void prep2_kernel(
    const float* __restrict__ w1, const float* __restrict__ w2,
    u16* __restrict__ w1t, u16* __restrict__ w2t)
{
  __shared__ float tS[64][65];
  const int z = blockIdx.z;
  const float* src; u16* dst; int R, C;
  if (z < 8) { src = w1 + (size_t)z * 1048576; dst = w1t + (size_t)z * 1048576; R = 512; C = 2048; }
  else       { src = w2 + (size_t)(z - 8) * 1048576; dst = w2t + (size_t)(z - 8) * 1048576; R = 2048; C = 512; }
  const int tc = C >> 6;
  const int r0 = (blockIdx.x / tc) * 64, c0 = (blockIdx.x % tc) * 64;
  const int tid = threadIdx.x;
  #pragma unroll
  for (int j = 0; j < 16; ++j) {
    int idx = j * 256 + tid;
    int r = idx >> 6, c = idx & 63;
    tS[r][c] = src[(size_t)(r0 + r) * C + c0 + c];
  }
  __syncthreads();
  #pragma unroll
  for (int j = 0; j < 16; ++j) {
    int idx = j * 256 + tid;
    int c = idx >> 6, r = idx & 63;
    dst[(size_t)(c0 + c) * R + r0 + r] = f2bf(tS[r][c]);
  }
}

// ---------------------------------------------------------------------------
// LN1: one wave per row (4 rows/block). f64 stats via shfl_xor butterfly.
__global__ __launch_bounds__(256) void ln1_kernel(
    const float* __restrict__ x, const float* __restrict__ g,
    const float* __restrict__ b, u16* __restrict__ hh, u16* __restrict__ hl)
{
  const int row = blockIdx.x * 4 + (threadIdx.x >> 6);
  const int lane = threadIdx.x & 63;
  const float* xr = x + (size_t)row * 512 + lane * 8;
  float4 a = *(const float4*)xr;
  float4 c = *(const float4*)(xr + 4);
  double s1 = (double)a.x + a.y + a.z + a.w + c.x + c.y + c.z + c.w;
  double s2 = (double)a.x * a.x + (double)a.y * a.y + (double)a.z * a.z + (double)a.w * a.w
            + (double)c.x * c.x + (double)c.y * c.y + (double)c.z * c.z + (double)c.w * c.w;
  #pragma unroll
  for (int off = 32; off; off >>= 1) {
    s1 += __shfl_xor(s1, off, 64);
    s2 += __shfl_xor(s2, off, 64);
  }
  double mu = s1 * (1.0 / 512.0);
  double var = s2 * (1.0 / 512.0) - mu * mu;
  double rs = 1.0 / sqrt(var + 1e-5);
  float4 ga = *(const float4*)(g + lane * 8);
  float4 gb = *(const float4*)(g + lane * 8 + 4);
  float4 ba = *(const float4*)(b + lane * 8);
  float4 bb = *(const float4*)(b + lane * 8 + 4);
  float vv[8] = {a.x, a.y, a.z, a.w, c.x, c.y, c.z, c.w};
  float gg[8] = {ga.x, ga.y, ga.z, ga.w, gb.x, gb.y, gb.z, gb.w};
  float cc[8] = {ba.x, ba.y, ba.z, ba.w, bb.x, bb.y, bb.z, bb.w};
  u16 oh[8], ol[8];
  #pragma unroll
  for (int j = 0; j < 8; ++j) {
    float t = (float)(((double)vv[j] - mu) * rs);
    float n0 = t * gg[j] + cc[j];
    f16 h = (f16)n0;
    oh[j] = f16b(h);
    ol[j] = f16b((f16)((n0 - (float)h) * 4096.0f));
  }
  size_t base = (size_t)row * 512 + lane * 8;
  *(short8*)(hh + base) = *(const short8*)oh;
  *(short8*)(hl + base) = *(const short8*)ol;
}

// ---------------------------------------------------------------------------
// QKV GEMM body: 8 waves, tile 128x128, split-f16 3-MFMA, 2-phase
// double-buffered global_load_lds with counted vmcnt. Output packed hi|lo u32.
// XCD remap (T1): XCD c owns 16 row-tiles; its 12 col-tiles run back-to-back.
__device__ __forceinline__ void qkv_body(
    int lid, u16* SMb,
    const u16* __restrict__ hh, const u16* __restrict__ hl,
    const u16* __restrict__ whi, const u16* __restrict__ wlo,
    const float* __restrict__ bq, const float* __restrict__ bk,
    const float* __restrict__ bv, u32* __restrict__ qkvh, int M0)
{
  const int tid = threadIdx.x;
  const int lane = tid & 63, w = tid >> 6;
  const int c8 = lid & 7, kk = lid >> 3;      // kk in [0,192)
  const int rt = c8 * 16 + kk / 12;           // row-tile [16c, 16c+16)
  const int ct = kk % 12;
  const int col0 = ct * 128;
  const int row0 = rt * 128;
  const int wr = w >> 2, wc = w & 3;          // wave tile 64r x 32c
  const int lr = lane & 15, lkq = lane >> 4;
  const int sx = (lkq ^ SWZF(lr)) * 8;
  const int lrow = lane >> 2;
  const int lcs = ((lane & 3) ^ SWZF(lrow)) * 8;

  const u16* gsrc[4];
  int loff[4];
  #pragma unroll
  for (int j = 0; j < 4; ++j) {
    const int q = w * 4 + j;
    loff[j] = q * 512;
    if (q < 8)       gsrc[j] = hh + (size_t)(M0 + row0 + q * 16 + lrow) * 512 + lcs;
    else if (q < 16) gsrc[j] = hl + (size_t)(M0 + row0 + (q - 8) * 16 + lrow) * 512 + lcs;
    else if (q < 24) gsrc[j] = whi + (size_t)(col0 + (q - 16) * 16 + lrow) * 512 + lcs;
    else             gsrc[j] = wlo + (size_t)(col0 + (q - 24) * 16 + lrow) * 512 + lcs;
  }

  f32x4 acch[4][2], accl[4][2];
  #pragma unroll
  for (int m = 0; m < 4; ++m)
    #pragma unroll
    for (int n = 0; n < 2; ++n) {
      f32x4 zz = {0.f, 0.f, 0.f, 0.f};
      acch[m][n] = zz; accl[m][n] = zz;
    }

  #pragma unroll
  for (int j = 0; j < 4; ++j) gl16(gsrc[j], &SMb[loff[j]]);
  #pragma unroll
  for (int j = 0; j < 4; ++j) gl16(gsrc[j] + 32, &SMb[16384 + loff[j]]);

  for (int kc = 0; kc < 16; ++kc) {
    if (kc == 15) asm volatile("s_waitcnt vmcnt(0)" ::: "memory");
    else          asm volatile("s_waitcnt vmcnt(4)" ::: "memory");
    __builtin_amdgcn_s_barrier();
    __builtin_amdgcn_sched_barrier(0);
    const u16* S = &SMb[(kc & 1) * 16384];
    f16x8 ah[4], al[4], bh[2], bl[2];
    #pragma unroll
    for (int m = 0; m < 4; ++m) {
      int r = wr * 64 + m * 16 + lr;
      ah[m] = *(const f16x8*)&S[r * 32 + sx];
      al[m] = *(const f16x8*)&S[4096 + r * 32 + sx];
    }
    #pragma unroll
    for (int n = 0; n < 2; ++n) {
      int c = wc * 32 + n * 16 + lr;
      bh[n] = *(const f16x8*)&S[8192 + c * 32 + sx];
      bl[n] = *(const f16x8*)&S[12288 + c * 32 + sx];
    }
    #pragma unroll
    for (int m = 0; m < 4; ++m)
      #pragma unroll
      for (int n = 0; n < 2; ++n) {
        acch[m][n] = MFMA16(ah[m], bh[n], acch[m][n]);
        accl[m][n] = MFMA16(ah[m], bl[n], accl[m][n]);
        accl[m][n] = MFMA16(al[m], bh[n], accl[m][n]);
      }
    __builtin_amdgcn_s_barrier();
    __builtin_amdgcn_sched_barrier(0);
    if (kc + 2 < 16) {
      #pragma unroll
      for (int j = 0; j < 4; ++j) gl16(gsrc[j] + (kc + 2) * 32, &SMb[(kc & 1) * 16384 + loff[j]]);
    }
  }
  #pragma unroll
  for (int m = 0; m < 4; ++m)
    #pragma unroll
    for (int n = 0; n < 2; ++n) {
      int col = col0 + wc * 32 + n * 16 + lr;
      float bb = (col < 512) ? bq[col] : (col < 1024) ? bk[col - 512] : bv[col - 1024];
      #pragma unroll
      for (int r = 0; r < 4; ++r) {
        int row = row0 + wr * 64 + m * 16 + lkq * 4 + r;
        float val = acch[m][n][r] + accl[m][n][r] * LO_SCALE + bb;
        f16 vh = (f16)val;
        f16 vl = (f16)((val - (float)vh) * 4096.0f);
        qkvh[(size_t)row * 1536 + col] = (u32)f16b(vh) | ((u32)f16b(vl) << 16);
      }
    }
}

__global__ __launch_bounds__(512, 2) void qkv_gemm_kernel(
    const u16* __restrict__ hh, const u16* __restrict__ hl,
    const u16* __restrict__ whi, const u16* __restrict__ wlo,
    const float* __restrict__ bq, const float* __restrict__ bk,
    const float* __restrict__ bv, u32* __restrict__ qkvh, int M0)
{
  __shared__ alignas(16) u16 SM[2][16384];
  qkv_body(blockIdx.x + 12 * blockIdx.y, &SM[0][0],
           hh, hl, whi, wlo, bq, bk, bv, qkvh, M0);
}

// ---------------------------------------------------------------------------
// wo GEMM body: clone of qkv template, M=16384 N=512 K=512, 512 blocks.
// Epilogue: dout = x + val (+bo). XCD remap: 16 row-tiles x 4 col-tiles/XCD.
__device__ __forceinline__ void wo_body(
    int lid, u16* SMb,
    const u16* __restrict__ cth, const u16* __restrict__ ctl,
    const u16* __restrict__ whi, const u16* __restrict__ wlo,
    const float* __restrict__ bo, const float* __restrict__ x,
    float* __restrict__ dout, int M0)
{
  const int tid = threadIdx.x;
  const int lane = tid & 63, w = tid >> 6;
  const int c8 = lid & 7, kk = lid >> 3;      // kk in [0,64)
  const int rt = c8 * 16 + (kk >> 2), ct = kk & 3;
  const int col0 = ct * 128;
  const int row0 = rt * 128;
  const int wr = w >> 2, wc = w & 3;
  const int lr = lane & 15, lkq = lane >> 4;
  const int sx = (lkq ^ SWZF(lr)) * 8;
  const int lrow = lane >> 2;
  const int lcs = ((lane & 3) ^ SWZF(lrow)) * 8;

  const u16* wh3 = whi + 3 * 262144;
  const u16* wl3 = wlo + 3 * 262144;

  const u16* gsrc[4];
  int loff[4];
  #pragma unroll
  for (int j = 0; j < 4; ++j) {
    const int q = w * 4 + j;
    loff[j] = q * 512;
    if (q < 8)       gsrc[j] = cth + (size_t)(row0 + q * 16 + lrow) * 512 + lcs;
    else if (q < 16) gsrc[j] = ctl + (size_t)(row0 + (q - 8) * 16 + lrow) * 512 + lcs;
    else if (q < 24) gsrc[j] = wh3 + (size_t)(col0 + (q - 16) * 16 + lrow) * 512 + lcs;
    else             gsrc[j] = wl3 + (size_t)(col0 + (q - 24) * 16 + lrow) * 512 + lcs;
  }

  f32x4 acch[4][2], accl[4][2];
  #pragma unroll
  for (int m = 0; m < 4; ++m)
    #pragma unroll
    for (int n = 0; n < 2; ++n) {
      f32x4 zz = {0.f, 0.f, 0.f, 0.f};
      acch[m][n] = zz; accl[m][n] = zz;
    }

  #pragma unroll
  for (int j = 0; j < 4; ++j) gl16(gsrc[j], &SMb[loff[j]]);
  #pragma unroll
  for (int j = 0; j < 4; ++j) gl16(gsrc[j] + 32, &SMb[16384 + loff[j]]);

  for (int kc = 0; kc < 16; ++kc) {
    if (kc == 15) asm volatile("s_waitcnt vmcnt(0)" ::: "memory");
    else          asm volatile("s_waitcnt vmcnt(4)" ::: "memory");
    __builtin_amdgcn_s_barrier();
    __builtin_amdgcn_sched_barrier(0);
    const u16* S = &SMb[(kc & 1) * 16384];
    f16x8 ah[4], al[4], bh[2], bl[2];
    #pragma unroll
    for (int m = 0; m < 4; ++m) {
      int r = wr * 64 + m * 16 + lr;
      ah[m] = *(const f16x8*)&S[r * 32 + sx];
      al[m] = *(const f16x8*)&S[4096 + r * 32 + sx];
    }
    #pragma unroll
    for (int n = 0; n < 2; ++n) {
      int c = wc * 32 + n * 16 + lr;
      bh[n] = *(const f16x8*)&S[8192 + c * 32 + sx];
      bl[n] = *(const f16x8*)&S[12288 + c * 32 + sx];
    }
    #pragma unroll
    for (int m = 0; m < 4; ++m)
      #pragma unroll
      for (int n = 0; n < 2; ++n) {
        acch[m][n] = MFMA16(ah[m], bh[n], acch[m][n]);
        accl[m][n] = MFMA16(ah[m], bl[n], accl[m][n]);
        accl[m][n] = MFMA16(al[m], bh[n], accl[m][n]);
      }
    __builtin_amdgcn_s_barrier();
    __builtin_amdgcn_sched_barrier(0);
    if (kc + 2 < 16) {
      #pragma unroll
      for (int j = 0; j < 4; ++j) gl16(gsrc[j] + (kc + 2) * 32, &SMb[(kc & 1) * 16384 + loff[j]]);
    }
  }
  #pragma unroll
  for (int m = 0; m < 4; ++m)
    #pragma unroll
    for (int n = 0; n < 2; ++n) {
      int col = col0 + wc * 32 + n * 16 + lr;
      float bvv = bo[col];
      #pragma unroll
      for (int r = 0; r < 4; ++r) {
        int row = row0 + wr * 64 + m * 16 + lkq * 4 + r;
        float val = acch[m][n][r] + accl[m][n][r] * LO_SCALE + bvv;
        size_t gi = (size_t)(M0 + row) * 512 + col;
        dout[gi] = x[gi] + val;
      }
    }
}

__global__ __launch_bounds__(512, 2) void wo_gemm_kernel(
    const u16* __restrict__ cth, const u16* __restrict__ ctl,
    const u16* __restrict__ whi, const u16* __restrict__ wlo,
    const float* __restrict__ bo, const float* __restrict__ x,
    float* __restrict__ dout, int M0)
{
  __shared__ alignas(16) u16 SM[2][16384];
  wo_body(blockIdx.x + 4 * blockIdx.y, &SM[0][0],
          cth, ctl, whi, wlo, bo, x, dout, M0);
}

// ---------------------------------------------------------------------------
// Attention only (per quarter): 32 tokens (2 seqs) per block, 8 waves.
__global__ __launch_bounds__(512) void attn_kernel(
    const u32* __restrict__ qkvh, u16* __restrict__ cth, u16* __restrict__ ctl)
{
  __shared__ alignas(16) u32 vS[16384];        // 64KB: packed V
  __shared__ float pS[8][16][17];

  const int tid = threadIdx.x;
  const int lane = tid & 63, w = tid >> 6;
  const int lr = lane & 15, lkq = lane >> 4;
  const int row0 = blockIdx.x * 32;

  #pragma unroll
  for (int i = 0; i < 8; ++i) {
    int chunk = w * 8 + i;
    const u32* src = qkvh + (size_t)(row0 + (chunk >> 1)) * 1536 + 1024 + (chunk & 1) * 256 + lane * 4;
    gl16((const u16*)src, (u16*)(vS + chunk * 256));
  }
  __syncthreads();

  const int h4 = w & 3, s = w >> 2;
  #pragma unroll
  for (int g = 0; g < 2; ++g) {
    const int h = g * 4 + h4;
    f16x8 qh[2], ql[2], kh[2], kl[2];
    #pragma unroll
    for (int dc = 0; dc < 2; ++dc) {
      const u32* qp = qkvh + (size_t)(row0 + s * 16 + lr) * 1536 + h * 64 + dc * 32 + lkq * 8;
      const u32* kp = qp + 512;
      uint4 q0 = *(const uint4*)qp, q1 = *(const uint4*)(qp + 4);
      uint4 k0 = *(const uint4*)kp, k1 = *(const uint4*)(kp + 4);
      u32 qu[8] = {q0.x, q0.y, q0.z, q0.w, q1.x, q1.y, q1.z, q1.w};
      u32 ku[8] = {k0.x, k0.y, k0.z, k0.w, k1.x, k1.y, k1.z, k1.w};
      #pragma unroll
      for (int i = 0; i < 8; ++i) {
        qh[dc][i] = b2h((u16)(qu[i] & 0xffffu)); ql[dc][i] = b2h((u16)(qu[i] >> 16));
        kh[dc][i] = b2h((u16)(ku[i] & 0xffffu)); kl[dc][i] = b2h((u16)(ku[i] >> 16));
      }
    }
    f32x4 sh = {0.f, 0.f, 0.f, 0.f}, sl = {0.f, 0.f, 0.f, 0.f};
    #pragma unroll
    for (int dc = 0; dc < 2; ++dc) {
      sh = MFMA16(qh[dc], kh[dc], sh);
      sl = MFMA16(qh[dc], kl[dc], sl);
      sl = MFMA16(ql[dc], kh[dc], sl);
    }
    float p_[4];
    #pragma unroll
    for (int r = 0; r < 4; ++r) {
      float sv = (sh[r] + sl[r] * LO_SCALE) * 0.125f;
      float mx = sv;
      #pragma unroll
      for (int off = 8; off; off >>= 1) mx = fmaxf(mx, __shfl_xor(mx, off, 16));
      float e = expf(sv - mx);
      float su = e;
      #pragma unroll
      for (int off = 8; off; off >>= 1) su += __shfl_xor(su, off, 16);
      p_[r] = e / su;
    }
    #pragma unroll
    for (int r = 0; r < 4; ++r) pS[w][lkq * 4 + r][lr] = p_[r];
    f16x8 pah, pal;
    #pragma unroll
    for (int jj = 0; jj < 8; ++jj) {
      float pv = (lkq < 2) ? pS[w][lr][lkq * 8 + jj] : 0.0f;
      f16 ph = (f16)pv;
      pah[jj] = ph;
      pal[jj] = (f16)((pv - (float)ph) * 4096.0f);
    }
    #pragma unroll
    for (int cf = 0; cf < 4; ++cf) {
      f16x8 vhf, vlf;
      #pragma unroll
      for (int jj = 0; jj < 8; ++jj) {
        u32 u = (lkq < 2) ? vS[(size_t)(s * 16 + lkq * 8 + jj) * 512 + h * 64 + cf * 16 + lr] : 0u;
        vhf[jj] = b2h((u16)(u & 0xffffu));
        vlf[jj] = b2h((u16)(u >> 16));
      }
      f32x4 ch = {0.f, 0.f, 0.f, 0.f}, cl = {0.f, 0.f, 0.f, 0.f};
      ch = MFMA16(pah, vhf, ch);
      cl = MFMA16(pah, vlf, cl);
      cl = MFMA16(pal, vhf, cl);
      #pragma unroll
      for (int r = 0; r < 4; ++r) {
        float cv = ch[r] + cl[r] * LO_SCALE;
        int row = row0 + s * 16 + lkq * 4 + r;
        int d = h * 64 + cf * 16 + lr;
        size_t gi = (size_t)row * 512 + d;
        f16 chv = (f16)cv;
        cth[gi] = f16b(chv);
        ctl[gi] = f16b((f16)((cv - (float)chv) * 4096.0f));
      }
    }
  }
}

// ---------------------------------------------------------------------------
// Router (reads dout = post-attn residual): one wave per token, no LDS.
// Also writes xn[tok] = bf16 LN2(dout[tok]) (gather fused away).
__global__ __launch_bounds__(256) void router_kernel(
    const float* __restrict__ xp, const float* __restrict__ g2,
    const float* __restrict__ b2ln, const float* __restrict__ rwt,
    const float* __restrict__ rb, float* __restrict__ stats,
    int* __restrict__ t2, u16* __restrict__ xn)
{
  const int tid = threadIdx.x;
  const int lane = tid & 63, w = tid >> 6;
  const int tok = blockIdx.x * 4 + w;
  const float* xr = xp + (size_t)tok * 512 + lane * 8;
  float4 a = *(const float4*)(xr);
  float4 b = *(const float4*)(xr + 4);
  double s1 = (double)a.x + a.y + a.z + a.w + b.x + b.y + b.z + b.w;
  double s2 = (double)a.x * a.x + (double)a.y * a.y + (double)a.z * a.z + (double)a.w * a.w
            + (double)b.x * b.x + (double)b.y * b.y + (double)b.z * b.z + (double)b.w * b.w;
  #pragma unroll
  for (int off = 32; off; off >>= 1) {
    s1 += __shfl_xor(s1, off, 64);
    s2 += __shfl_xor(s2, off, 64);
  }
  double mu = s1 * (1.0 / 512.0);
  double var = s2 * (1.0 / 512.0) - mu * mu;
  double rs = 1.0 / sqrt(var + 1e-5);
  if (lane == 0) {
    stats[tok * 2] = (float)mu;
    stats[tok * 2 + 1] = (float)rs;
  }
  float4 ga = *(const float4*)(g2 + lane * 8);
  float4 gb = *(const float4*)(g2 + lane * 8 + 4);
  float4 ca = *(const float4*)(b2ln + lane * 8);
  float4 cb = *(const float4*)(b2ln + lane * 8 + 4);
  // --- xn write: EXACT replica of old gather's f32 math (f32 mu/rs) ---
  {
    float muf = (float)mu, rsf = (float)rs;
    u16 ox[8];
    ox[0] = f2bf((a.x - muf) * rsf * ga.x + ca.x);
    ox[1] = f2bf((a.y - muf) * rsf * ga.y + ca.y);
    ox[2] = f2bf((a.z - muf) * rsf * ga.z + ca.z);
    ox[3] = f2bf((a.w - muf) * rsf * ga.w + ca.w);
    ox[4] = f2bf((b.x - muf) * rsf * gb.x + cb.x);
    ox[5] = f2bf((b.y - muf) * rsf * gb.y + cb.y);
    ox[6] = f2bf((b.z - muf) * rsf * gb.z + cb.z);
    ox[7] = f2bf((b.w - muf) * rsf * gb.w + cb.w);
    *(short8*)(xn + (size_t)tok * 512 + lane * 8) = *(const short8*)ox;
  }
  float h[8];
  h[0] = (float)(((double)a.x - mu) * rs * (double)ga.x + (double)ca.x);
  h[1] = (float)(((double)a.y - mu) * rs * (double)ga.y + (double)ca.y);
  h[2] = (float)(((double)a.z - mu) * rs * (double)ga.z + (double)ca.z);
  h[3] = (float)(((double)a.w - mu) * rs * (double)ga.w + (double)ca.w);
  h[4] = (float)(((double)b.x - mu) * rs * (double)gb.x + (double)cb.x);
  h[5] = (float)(((double)b.y - mu) * rs * (double)gb.y + (double)cb.y);
  h[6] = (float)(((double)b.z - mu) * rs * (double)gb.z + (double)cb.z);
  h[7] = (float)(((double)b.w - mu) * rs * (double)gb.w + (double)cb.w);
  double acc[8];
  #pragma unroll
  for (int e = 0; e < 8; ++e) {
    const float* wp = rwt + e * 512 + lane * 8;
    float4 w0 = *(const float4*)wp;
    float4 w1 = *(const float4*)(wp + 4);
    acc[e] = (double)h[0] * (double)w0.x + (double)h[1] * (double)w0.y
           + (double)h[2] * (double)w0.z + (double)h[3] * (double)w0.w
           + (double)h[4] * (double)w1.x + (double)h[5] * (double)w1.y
           + (double)h[6] * (double)w1.z + (double)h[7] * (double)w1.w;
  }
  #pragma unroll
  for (int e = 0; e < 8; ++e) {
    acc[e] += __shfl_xor(acc[e], 8, 64);
    acc[e] += __shfl_xor(acc[e], 16, 64);
    acc[e] += __shfl_xor(acc[e], 32, 64);
  }
  const int b0 = lane & 1, b1 = (lane >> 1) & 1, b2_ = (lane >> 2) & 1;
  double t4[4];
  #pragma unroll
  for (int k = 0; k < 4; ++k) {
    double mine = b0 ? acc[2 * k + 1] : acc[2 * k];
    double send = b0 ? acc[2 * k] : acc[2 * k + 1];
    t4[k] = mine + __shfl_xor(send, 1, 64);
  }
  double u2[2];
  #pragma unroll
  for (int k = 0; k < 2; ++k) {
    double mine = b1 ? t4[2 * k + 1] : t4[2 * k];
    double send = b1 ? t4[2 * k] : t4[2 * k + 1];
    u2[k] = mine + __shfl_xor(send, 2, 64);
  }
  {
    double mine = b2_ ? u2[1] : u2[0];
    double send = b2_ ? u2[0] : u2[1];
    double tot = mine + __shfl_xor(send, 4, 64);
    const int e = lane & 7;
    double lg = tot + (double)rb[e];
    double vv = lg; int ix = e;
    #pragma unroll
    for (int off = 4; off; off >>= 1) {
      double ov = __shfl_xor(vv, off, 8);
      int oi = __shfl_xor(ix, off, 8);
      if (ov > vv || (ov == vv && oi < ix)) { vv = ov; ix = oi; }
    }
    double v2 = (e == ix) ? -1.0e300 : lg; int ix2 = e;
    #pragma unroll
    for (int off = 4; off; off >>= 1) {
      double ov = __shfl_xor(v2, off, 8);
      int oi = __shfl_xor(ix2, off, 8);
      if (ov > v2 || (ov == v2 && oi < ix2)) { v2 = ov; ix2 = oi; }
    }
    if (lane == 0) t2[tok] = ix | (ix2 << 8);
  }
}

// ---------------------------------------------------------------------------
// Routing scans (all deterministic, zero atomics).
__global__ __launch_bounds__(256) void scan1_kernel(
    const int* __restrict__ t2, int* __restrict__ blkcnt, int* __restrict__ ranks)
{
  __shared__ u32 mask[256];
  __shared__ u16 rk[256][8];
  const int t = threadIdx.x, tok = blockIdx.x * 256 + t;
  const int p = t2[tok];
  const int e1 = p & 0xff, e2 = (p >> 8) & 0xff;
  mask[t] = (1u << e1) | (1u << e2);
  __syncthreads();
  if (t < 8) {
    int c = 0;
    for (int i = 0; i < 256; ++i) { rk[i][t] = (u16)c; c += (mask[i] >> t) & 1u; }
    blkcnt[blockIdx.x * 8 + t] = c;
  }
  __syncthreads();
  ranks[tok] = (int)rk[t][e1] | ((int)rk[t][e2] << 16);
}

__global__ void scan2_kernel(const int* __restrict__ blkcnt,
                             int* __restrict__ offs)
{
  const int e = threadIdx.x;
  if (e < 8) {
    int off = 0;
    for (int b = 0; b < 256; ++b) { offs[b * 8 + e] = off; off += blkcnt[b * 8 + e]; }
  }
}

// scan3: winner determination + per-block winner counts/ranks (scan1 pattern).
__global__ __launch_bounds__(256) void scan3_kernel(
    const int* __restrict__ t2, const int* __restrict__ ranks,
    const int* __restrict__ offs, int* __restrict__ wblkcnt,
    int* __restrict__ wrk_tok)
{
  __shared__ u32 wmask[256];
  __shared__ u16 wrk[256][8];
  const int t = threadIdx.x, blk = blockIdx.x, tok = blk * 256 + t;
  const int p = t2[tok];
  const int e1 = p & 0xff, e2 = (p >> 8) & 0xff;
  const int r = ranks[tok];
  const int s1 = offs[blk * 8 + e1] + (r & 0xffff);
  const int s2 = offs[blk * 8 + e2] + ((r >> 16) & 0xffff);
  int w = -1;
  if (s1 < CAP) w = (e1 > w) ? e1 : w;
  if (s2 < CAP) w = (e2 > w) ? e2 : w;
  wmask[t] = (w >= 0) ? (1u << w) : 0u;
  __syncthreads();
  if (t < 8) {
    int c = 0;
    for (int i = 0; i < 256; ++i) { wrk[i][t] = (u16)c; c += (wmask[i] >> t) & 1u; }
    wblkcnt[blk * 8 + t] = c;
  }
  __syncthreads();
  wrk_tok[tok] = (w >= 0) ? ((int)wrk[t][w] | (w << 16)) : -1;
}

// scan4: prefix-sum winner block counts -> per-block winner offsets + totals.
__global__ void scan4_kernel(const int* __restrict__ wblkcnt,
                             int* __restrict__ woffs, int* __restrict__ wcnt)
{
  const int e = threadIdx.x;
  if (e < 8) {
    int off = 0;
    for (int b = 0; b < 256; ++b) { woffs[b * 8 + e] = off; off += wblkcnt[b * 8 + e]; }
    wcnt[e] = off;
  }
}

// scan5: scatter winner tokens to compacted per-expert lists (deterministic).
__global__ __launch_bounds__(256) void scan5_kernel(
    const int* __restrict__ wrk_tok, const int* __restrict__ woffs,
    int* __restrict__ wlist)
{
  const int t = threadIdx.x, blk = blockIdx.x, tok = blk * 256 + t;
  const int pr = wrk_tok[tok];
  if (pr >= 0) {
    const int w = pr >> 16, rk = pr & 0xffff;
    wlist[w * CAPP + woffs[blk * 8 + w] + rk] = tok;
  }
}

// ---------------------------------------------------------------------------
// FFN GEMM body, 8-wave 2-RING variant (TLP follow-up to R18's win): tile
// 128 rows x 256 cols, 512 threads / 8 waves (2x4), wave owns 64x64 (acc
// 4x4); staging 3 gl16/thread/buffer. DOUBLE-buffered with the qkv-proven
// 2-barrier schedule (wait vmcnt(3) -> barrier -> MFMA -> barrier -> stage
// kc+2 into the freed buffer). 48KB LDS -> 3 blocks/CU -> 24 waves/CU
// (vs R18's 16). Per-output K-order and epilogue math unchanged ->
// bit-identical result.
// XCD remap: round-robin row-tile -> XCD (wy = (pr%13)*8 + c8). Padded
// wy==103 exits; tiles beyond the expert's winner count exit (pre-barrier).
// EPI 0 (ffn1): A = xn with per-lane winner-token indirection; GELU -> hid.
// EPI 1 (ffn2): scatter += val into dout for all rows < wcnt (all winners).
template<int EPI, int NKC, int AST, int BST, int NX>
__device__ __forceinline__ void ffn_body(
    int lid, u16* SMb,
    const u16* __restrict__ A, const u16* __restrict__ Bw,
    const float* __restrict__ bias, u16* __restrict__ outb,
    const int* __restrict__ list, const int* __restrict__ cnts,
    float* __restrict__ dout, int ebase)
{
  const int c8 = lid & 7;
  const int kk = lid >> 3;              // [0, NX*26)
  const int wx = kk & (NX - 1);
  const int pr = kk / NX;               // [0, 26)
  const int wz = pr / 13;
  const int wy = (pr % 13) * 8 + c8;    // round-robin row-tile -> XCD
  if (wy >= 103) return;                // padded tile (uniform exit, pre-barrier)
  const int ez = wz;
  const int expert = ebase + ez;
  const int cnt = cnts[expert];
  const int row0 = wy * 128;
  if (row0 >= cnt) return;              // winner-compacted tail (uniform exit)
  const int tid = threadIdx.x;
  const int lane = tid & 63, w = tid >> 6;   // 8 waves
  const int wr = w >> 2, wc = w & 3;         // wave tile: 64 rows x 64 cols
  const int colb = wx * 256;
  const int lr = lane & 15, lkq = lane >> 4;
  const int sx = (lkq ^ SWZF(lr)) * 8;
  const int lrow = lane >> 2;
  const int lcs = ((lane & 3) ^ SWZF(lrow)) * 8;

  const u16* Bp = Bw + (size_t)expert * 1048576;

  // staging: 24 chunks (A 8 + B 16) over 8 waves = 3 chunks/wave
  const u16* gsrc[3];
  int loff[3];
  #pragma unroll
  for (int j = 0; j < 3; ++j) {
    const int c = w * 3 + j;             // 0..23 (wave-uniform)
    if (c < 8) {
      const int q = c;
      int arow = row0 + q * 16 + lrow;
      if (EPI == 0) {
        int tok = list[(size_t)expert * CAPP + arow] & 65535;
        gsrc[j] = A + (size_t)tok * 512 + lcs;
      } else {
        gsrc[j] = A + (size_t)ez * CAPP * 2048 + (size_t)arow * AST + lcs;
      }
      loff[j] = q * 512;
    } else {
      const int q = c - 8;
      gsrc[j] = Bp + (size_t)(colb + q * 16 + lrow) * BST + lcs;
      loff[j] = 4096 + q * 512;
    }
  }

  f32x4 acc[4][4];
  #pragma unroll
  for (int m = 0; m < 4; ++m)
    #pragma unroll
    for (int n = 0; n < 4; ++n) {
      f32x4 zz = {0.f, 0.f, 0.f, 0.f};
      acc[m][n] = zz;
    }

  #pragma unroll
  for (int j = 0; j < 3; ++j) gl16(gsrc[j], &SMb[loff[j]]);
  #pragma unroll
  for (int j = 0; j < 3; ++j) gl16(gsrc[j] + 32, &SMb[12288 + loff[j]]);

  for (int kc = 0; kc < NKC; ++kc) {
    if (kc == NKC - 1) asm volatile("s_waitcnt vmcnt(0)" ::: "memory");
    else               asm volatile("s_waitcnt vmcnt(3)" ::: "memory");
    __builtin_amdgcn_s_barrier();
    __builtin_amdgcn_sched_barrier(0);
    const u16* S = &SMb[(kc & 1) * 12288];
    short8 af[4], bf[4];
    #pragma unroll
    for (int m = 0; m < 4; ++m)
      af[m] = *(const short8*)&S[(wr * 64 + m * 16 + lr) * 32 + sx];
    #pragma unroll
    for (int n = 0; n < 4; ++n)
      bf[n] = *(const short8*)&S[4096 + (wc * 64 + n * 16 + lr) * 32 + sx];
    #pragma unroll
    for (int m = 0; m < 4; ++m)
      #pragma unroll
      for (int n = 0; n < 4; ++n)
        acc[m][n] = MFMAB(af[m], bf[n], acc[m][n]);
    __builtin_amdgcn_s_barrier();
    __builtin_amdgcn_sched_barrier(0);
    if (kc + 2 < NKC) {
      #pragma unroll
      for (int j = 0; j < 3; ++j) gl16(gsrc[j] + (kc + 2) * 32, &SMb[(kc & 1) * 12288 + loff[j]]);
    }
  }

  if (EPI == 0) {
    #pragma unroll
    for (int m = 0; m < 4; ++m)
      #pragma unroll
      for (int n = 0; n < 4; ++n) {
        int col = colb + wc * 64 + n * 16 + lr;
        float bvv = bias[expert * 2048 + col];
        #pragma unroll
        for (int r = 0; r < 4; ++r) {
          int row = row0 + wr * 64 + m * 16 + lkq * 4 + r;
          float val = acc[m][n][r] + bvv;
          outb[(size_t)ez * CAPP * 2048 + (size_t)row * 2048 + col] = f2bf(gelu_f(val));
        }
      }
  } else {
    const int* gidx = list + (size_t)expert * CAPP;
    #pragma unroll
    for (int m = 0; m < 4; ++m) {
      int rowb = row0 + wr * 64 + m * 16 + lkq * 4;
      #pragma unroll
      for (int r = 0; r < 4; ++r) {
        int row = rowb + r;
        if (row < cnt) {
          int tok = gidx[row];
          #pragma unroll
          for (int n = 0; n < 4; ++n) {
            int col = colb + wc * 64 + n * 16 + lr;
            float val = acc[m][n][r] + bias[expert * 512 + col];
            size_t oi = (size_t)tok * 512 + col;
            dout[oi] = dout[oi] + val;   // dout holds x2; same-thread RMW
          }
        }
      }
    }
  }
}

// Merged dispatch: role-2 (ffn2 of previous expert pair, long 64-step blocks)
// occupies bx < nb2 so it launches FIRST; role-1 (ffn1 of current pair) fills
// the remaining CU slots around it.
__global__ __launch_bounds__(512, 6) void ffn_merged_kernel(
    const u16* __restrict__ xn, const u16* __restrict__ w1t,
    const float* __restrict__ b1, u16* __restrict__ hidW,
    const u16* __restrict__ hidR, const u16* __restrict__ w2t,
    const float* __restrict__ b2,
    const int* __restrict__ wlist, const int* __restrict__ wcnt,
    float* __restrict__ dout, int nb2, int eb1, int eb2)
{
  __shared__ alignas(16) u16 SM[2][12288];   // 48KB -> 3 blocks/CU (24 waves)
  const int bx = blockIdx.x;
  if (bx < nb2) {
    ffn_body<1, 64, 2048, 2048, 2>(bx, &SM[0][0], hidR, w2t, b2, nullptr,
                                   wlist, wcnt, dout, eb2);
  } else {
    ffn_body<0, 16, 512, 512, 8>(bx - nb2, &SM[0][0], xn, w1t, b1, hidW,
                                 wlist, wcnt, nullptr, eb1);
  }
}

// ---------------------------------------------------------------------------
extern "C" void kernel_launch(void* const* d_in, const int* in_sizes, int n_in,
                              void* d_out, int out_size, void* d_ws, size_t ws_size,
                              hipStream_t stream) {
  const float* x    = (const float*)d_in[0];
  const float* ln1g = (const float*)d_in[1];
  const float* ln1b = (const float*)d_in[2];
  const float* ln2g = (const float*)d_in[3];
  const float* ln2b = (const float*)d_in[4];
  const float* wq   = (const float*)d_in[5];
  const float* bq   = (const float*)d_in[6];
  const float* wk   = (const float*)d_in[7];
  const float* bk   = (const float*)d_in[8];
  const float* wv   = (const float*)d_in[9];
  const float* bv   = (const float*)d_in[10];
  const float* wo   = (const float*)d_in[11];
  const float* bo   = (const float*)d_in[12];
  const float* rw   = (const float*)d_in[13];
  const float* rb   = (const float*)d_in[14];
  const float* w1   = (const float*)d_in[15];
  const float* b1   = (const float*)d_in[16];
  const float* w2   = (const float*)d_in[17];
  const float* b2   = (const float*)d_in[18];
  float* dout = (float*)d_out;

  char* ws = (char*)d_ws;
  u16*   hh   = (u16*)(ws + 0LL);            // [65536][512] f16 hi
  u16*   hl   = (u16*)(ws + 67108864LL);     // lo plane
  u32*   qkvh = (u32*)(ws + 134217728LL);    // [16384][1536] packed quarter
  u16*   cth  = (u16*)(ws + 234881024LL);    // ctx hi quarter (dead before router)
  u16*   ctl  = (u16*)(ws + 251658240LL);    // ctx lo quarter
  u16*   whi  = (u16*)(ws + 369098752LL);
  u16*   wlo  = (u16*)(ws + 371195904LL);
  float* rwt  = (float*)(ws + 373293056LL);
  float* st2  = (float*)(ws + 373309440LL);
  int*   t2   = (int*)(ws + 373833728LL);
  int*   rks  = (int*)(ws + 374095872LL);
  int*   bc   = (int*)(ws + 374358016LL);
  int*   offs = (int*)(ws + 374366208LL);
  int*   wcnt = (int*)(ws + 374374400LL);    // 8 winner counts
  int*   wlst = (int*)(ws + 374374464LL);    // [8][CAPP] winner token lists
  int*   wrkt = (int*)(ws + 374796352LL);    // [65536] packed (winner, rank)
  int*   wbc  = (int*)(ws + 375058496LL);    // [256][8] winner block counts
  int*   wofs = (int*)(ws + 375066688LL);    // [256][8] winner block offsets
  // aliases (regions dead by the time these are written)
  u16*   w1t  = (u16*)(ws + 0LL);            // in hh (dead after qkv q3)
  u16*   w2t  = (u16*)(ws + 16777216LL);     // in hh
  u16*   xn   = (u16*)(ws + 33554432LL);     // [65536][512] bf16 (32..96MB; hh/hl dead)
  u16*   hid0 = (u16*)(ws + 100663296LL);    // 2 experts x CAPP x 2048 bf16 (103MB)
  u16*   hid1 = (u16*)(ws + 208666624LL);    // second buffer (ends ~302MB < whi)

  prep1_kernel<<<dim3(1024, 1, 5), 256, 0, stream>>>(wq, wk, wv, wo, rw, whi, wlo, rwt);
  ln1_kernel<<<16384, 256, 0, stream>>>(x, ln1g, ln1b, hh, hl);
  for (int q = 0; q < 4; ++q) {
    qkv_gemm_kernel<<<dim3(12, 128), 512, 0, stream>>>(
        hh, hl, whi, wlo, bq, bk, bv, qkvh, q * QTOK);
    attn_kernel<<<512, 512, 0, stream>>>(qkvh, cth, ctl);
    wo_gemm_kernel<<<dim3(4, 128), 512, 0, stream>>>(
        cth, ctl, whi, wlo, bo, x, dout, q * QTOK);
  }
  prep2_kernel<<<dim3(256, 1, 16), 256, 0, stream>>>(w1, w2, w1t, w2t);
  router_kernel<<<16384, 256, 0, stream>>>(dout, ln2g, ln2b, rwt, rb, st2, t2, xn);
  scan1_kernel<<<256, 256, 0, stream>>>(t2, bc, rks);
  scan2_kernel<<<1, 256, 0, stream>>>(bc, offs);
  scan3_kernel<<<256, 256, 0, stream>>>(t2, rks, offs, wbc, wrkt);
  scan4_kernel<<<1, 256, 0, stream>>>(wbc, wofs, wcnt);
  scan5_kernel<<<256, 256, 0, stream>>>(wrkt, wofs, wlst);
  // 5-stage software pipeline: stage s runs ffn1(experts 2s,2s+1) into
  // hid[s&1] concurrently with ffn2(experts 2s-2,2s-1) from hid[(s-1)&1].
  // Winner-compacted: tiles beyond each expert's winner count early-exit;
  // round-robin row-tile->XCD mapping keeps the active prefix balanced.
  // 8-wave 2-ring blocks (48KB LDS): 24 waves/CU at the same tile.
  for (int s = 0; s < 5; ++s) {
    const int nb1 = (s < 4) ? 1664 : 0;   // 8*104*2 (incl. padded tiles)
    const int nb2 = (s > 0) ? 416 : 0;    // 2*104*2
    u16* hw = (s & 1) ? hid1 : hid0;
    const u16* hr = ((s - 1) & 1) ? hid1 : hid0;
    ffn_merged_kernel<<<nb1 + nb2, 512, 0, stream>>>(
        xn, w1t, b1, hw, hr, w2t, b2, wlst, wcnt, dout,
        nb2, s * 2, (s - 1) * 2);
  }
}

// Round 20
// 1168.391 us; speedup vs baseline: 2.6306x; 2.6306x over previous
//
#include <hip/hip_runtime.h>
#include <hip/hip_bf16.h>
#include <math.h>

typedef unsigned short u16;
typedef unsigned int u32;
typedef _Float16 f16;
typedef __attribute__((ext_vector_type(8))) _Float16 f16x8;
typedef __attribute__((ext_vector_type(8))) short short8;
typedef __attribute__((ext_vector_type(4))) float f32x4;

#define TTOK 65536
#define QTOK 16384
#define CAP 13108
#define CAPP 13184  // 103*128

#define MFMA16(a, b, c) __builtin_amdgcn_mfma_f32_16x16x32_f16(a, b, c, 0, 0, 0)
#define MFMAB(a, b, c) __builtin_amdgcn_mfma_f32_16x16x32_bf16(a, b, c, 0, 0, 0)
#define LO_SCALE 2.44140625e-4f  // 2^-12

// 3-bit XOR swizzle: slot s of row r holds col-seg s ^ F(r).
#define SWZF(r) (((r) & 3) ^ ((((r) >> 2) & 1) << 1))

__device__ __forceinline__ u16 f2bf(float f) {
  union { float f; u32 u; } v; v.f = f;
  u32 r = v.u + 0x7fffu + ((v.u >> 16) & 1u);
  return (u16)(r >> 16);
}
__device__ __forceinline__ u16 f16b(f16 h) {
  union { f16 h; u16 u; } v; v.h = h; return v.u;
}
__device__ __forceinline__ f16 b2h(u16 u) {
  union { u16 s; f16 h; } v; v.s = u; return v.h;
}
// Fast exact GELU: A&S 7.1.26 erf, |err|<=1.5e-7 (far below bf16 noise).
__device__ __forceinline__ float gelu_f(float x) {
  float z = fabsf(x) * 0.70710678118654752f;
  float t = __builtin_amdgcn_rcpf(1.0f + 0.3275911f * z);
  float p = t * (0.254829592f + t * (-0.284496736f + t * (1.421413741f
          + t * (-1.453152027f + t * 1.061405429f))));
  float er = 1.0f - p * __expf(-z * z);
  er = (x < 0.0f) ? -er : er;
  return 0.5f * x * (1.0f + er);
}
// async global->LDS, 16B per lane; dest = wave-uniform base + lane*16
__device__ __forceinline__ void gl16(const u16* g, u16* l) {
  __builtin_amdgcn_global_load_lds(
      (const __attribute__((address_space(1))) u32*)(const void*)g,
      (__attribute__((address_space(3))) u32*)(void*)l, 16, 0, 0);
}

// ---------------------------------------------------------------------------
// prep1: wq/wk/wv/wo [K=512][N=512] f32 -> f16 hi/lo planes [2048][512];
// router_w -> rwt [8][512] f32.
__global__ __launch_bounds__(256) void prep1_kernel(
    const float* __restrict__ wq, const float* __restrict__ wk,
    const float* __restrict__ wv, const float* __restrict__ wo,
    const float* __restrict__ rw,
    u16* __restrict__ whi, u16* __restrict__ wlo, float* __restrict__ rwt)
{
  const int z = blockIdx.z;
  int idx = blockIdx.x * 256 + threadIdx.x;
  if (z == 4) {
    if (idx < 4096) {
      int n = idx >> 9, k = idx & 511;
      rwt[idx] = rw[k * 8 + n];
    }
    return;
  }
  const float* src = (z == 0) ? wq : (z == 1) ? wk : (z == 2) ? wv : wo;
  int n = idx >> 9, k = idx & 511;
  float v = src[k * 512 + n];
  f16 h = (f16)v;
  f16 l = (f16)((v - (float)h) * 4096.0f);
  whi[z * 262144 + idx] = f16b(h);
  wlo[z * 262144 + idx] = f16b(l);
}

// ---------------------------------------------------------------------------
// prep2: LDS-tiled transpose to bf16.
__global__ __launch_bounds__(256) void prep2_kernel(
    const float* __restrict__ w1, const float* __restrict__ w2,
    u16* __restrict__ w1t, u16* __restrict__ w2t)
{
  __shared__ float tS[64][65];
  const int z = blockIdx.z;
  const float* src; u16* dst; int R, C;
  if (z < 8) { src = w1 + (size_t)z * 1048576; dst = w1t + (size_t)z * 1048576; R = 512; C = 2048; }
  else       { src = w2 + (size_t)(z - 8) * 1048576; dst = w2t + (size_t)(z - 8) * 1048576; R = 2048; C = 512; }
  const int tc = C >> 6;
  const int r0 = (blockIdx.x / tc) * 64, c0 = (blockIdx.x % tc) * 64;
  const int tid = threadIdx.x;
  #pragma unroll
  for (int j = 0; j < 16; ++j) {
    int idx = j * 256 + tid;
    int r = idx >> 6, c = idx & 63;
    tS[r][c] = src[(size_t)(r0 + r) * C + c0 + c];
  }
  __syncthreads();
  #pragma unroll
  for (int j = 0; j < 16; ++j) {
    int idx = j * 256 + tid;
    int c = idx >> 6, r = idx & 63;
    dst[(size_t)(c0 + c) * R + r0 + r] = f2bf(tS[r][c]);
  }
}

// ---------------------------------------------------------------------------
// LN1: one wave per row (4 rows/block). f64 stats via shfl_xor butterfly.
__global__ __launch_bounds__(256) void ln1_kernel(
    const float* __restrict__ x, const float* __restrict__ g,
    const float* __restrict__ b, u16* __restrict__ hh, u16* __restrict__ hl)
{
  const int row = blockIdx.x * 4 + (threadIdx.x >> 6);
  const int lane = threadIdx.x & 63;
  const float* xr = x + (size_t)row * 512 + lane * 8;
  float4 a = *(const float4*)xr;
  float4 c = *(const float4*)(xr + 4);
  double s1 = (double)a.x + a.y + a.z + a.w + c.x + c.y + c.z + c.w;
  double s2 = (double)a.x * a.x + (double)a.y * a.y + (double)a.z * a.z + (double)a.w * a.w
            + (double)c.x * c.x + (double)c.y * c.y + (double)c.z * c.z + (double)c.w * c.w;
  #pragma unroll
  for (int off = 32; off; off >>= 1) {
    s1 += __shfl_xor(s1, off, 64);
    s2 += __shfl_xor(s2, off, 64);
  }
  double mu = s1 * (1.0 / 512.0);
  double var = s2 * (1.0 / 512.0) - mu * mu;
  double rs = 1.0 / sqrt(var + 1e-5);
  float4 ga = *(const float4*)(g + lane * 8);
  float4 gb = *(const float4*)(g + lane * 8 + 4);
  float4 ba = *(const float4*)(b + lane * 8);
  float4 bb = *(const float4*)(b + lane * 8 + 4);
  float vv[8] = {a.x, a.y, a.z, a.w, c.x, c.y, c.z, c.w};
  float gg[8] = {ga.x, ga.y, ga.z, ga.w, gb.x, gb.y, gb.z, gb.w};
  float cc[8] = {ba.x, ba.y, ba.z, ba.w, bb.x, bb.y, bb.z, bb.w};
  u16 oh[8], ol[8];
  #pragma unroll
  for (int j = 0; j < 8; ++j) {
    float t = (float)(((double)vv[j] - mu) * rs);
    float n0 = t * gg[j] + cc[j];
    f16 h = (f16)n0;
    oh[j] = f16b(h);
    ol[j] = f16b((f16)((n0 - (float)h) * 4096.0f));
  }
  size_t base = (size_t)row * 512 + lane * 8;
  *(short8*)(hh + base) = *(const short8*)oh;
  *(short8*)(hl + base) = *(const short8*)ol;
}

// ---------------------------------------------------------------------------
// QKV GEMM body: 8 waves, tile 128x128, split-f16 3-MFMA, 2-phase
// double-buffered global_load_lds with counted vmcnt. Output packed hi|lo u32.
// XCD remap (T1): XCD c owns 16 row-tiles; its 12 col-tiles run back-to-back.
__device__ __forceinline__ void qkv_body(
    int lid, u16* SMb,
    const u16* __restrict__ hh, const u16* __restrict__ hl,
    const u16* __restrict__ whi, const u16* __restrict__ wlo,
    const float* __restrict__ bq, const float* __restrict__ bk,
    const float* __restrict__ bv, u32* __restrict__ qkvh, int M0)
{
  const int tid = threadIdx.x;
  const int lane = tid & 63, w = tid >> 6;
  const int c8 = lid & 7, kk = lid >> 3;      // kk in [0,192)
  const int rt = c8 * 16 + kk / 12;           // row-tile [16c, 16c+16)
  const int ct = kk % 12;
  const int col0 = ct * 128;
  const int row0 = rt * 128;
  const int wr = w >> 2, wc = w & 3;          // wave tile 64r x 32c
  const int lr = lane & 15, lkq = lane >> 4;
  const int sx = (lkq ^ SWZF(lr)) * 8;
  const int lrow = lane >> 2;
  const int lcs = ((lane & 3) ^ SWZF(lrow)) * 8;

  const u16* gsrc[4];
  int loff[4];
  #pragma unroll
  for (int j = 0; j < 4; ++j) {
    const int q = w * 4 + j;
    loff[j] = q * 512;
    if (q < 8)       gsrc[j] = hh + (size_t)(M0 + row0 + q * 16 + lrow) * 512 + lcs;
    else if (q < 16) gsrc[j] = hl + (size_t)(M0 + row0 + (q - 8) * 16 + lrow) * 512 + lcs;
    else if (q < 24) gsrc[j] = whi + (size_t)(col0 + (q - 16) * 16 + lrow) * 512 + lcs;
    else             gsrc[j] = wlo + (size_t)(col0 + (q - 24) * 16 + lrow) * 512 + lcs;
  }

  f32x4 acch[4][2], accl[4][2];
  #pragma unroll
  for (int m = 0; m < 4; ++m)
    #pragma unroll
    for (int n = 0; n < 2; ++n) {
      f32x4 zz = {0.f, 0.f, 0.f, 0.f};
      acch[m][n] = zz; accl[m][n] = zz;
    }

  #pragma unroll
  for (int j = 0; j < 4; ++j) gl16(gsrc[j], &SMb[loff[j]]);
  #pragma unroll
  for (int j = 0; j < 4; ++j) gl16(gsrc[j] + 32, &SMb[16384 + loff[j]]);

  for (int kc = 0; kc < 16; ++kc) {
    if (kc == 15) asm volatile("s_waitcnt vmcnt(0)" ::: "memory");
    else          asm volatile("s_waitcnt vmcnt(4)" ::: "memory");
    __builtin_amdgcn_s_barrier();
    __builtin_amdgcn_sched_barrier(0);
    const u16* S = &SMb[(kc & 1) * 16384];
    f16x8 ah[4], al[4], bh[2], bl[2];
    #pragma unroll
    for (int m = 0; m < 4; ++m) {
      int r = wr * 64 + m * 16 + lr;
      ah[m] = *(const f16x8*)&S[r * 32 + sx];
      al[m] = *(const f16x8*)&S[4096 + r * 32 + sx];
    }
    #pragma unroll
    for (int n = 0; n < 2; ++n) {
      int c = wc * 32 + n * 16 + lr;
      bh[n] = *(const f16x8*)&S[8192 + c * 32 + sx];
      bl[n] = *(const f16x8*)&S[12288 + c * 32 + sx];
    }
    #pragma unroll
    for (int m = 0; m < 4; ++m)
      #pragma unroll
      for (int n = 0; n < 2; ++n) {
        acch[m][n] = MFMA16(ah[m], bh[n], acch[m][n]);
        accl[m][n] = MFMA16(ah[m], bl[n], accl[m][n]);
        accl[m][n] = MFMA16(al[m], bh[n], accl[m][n]);
      }
    __builtin_amdgcn_s_barrier();
    __builtin_amdgcn_sched_barrier(0);
    if (kc + 2 < 16) {
      #pragma unroll
      for (int j = 0; j < 4; ++j) gl16(gsrc[j] + (kc + 2) * 32, &SMb[(kc & 1) * 16384 + loff[j]]);
    }
  }
  #pragma unroll
  for (int m = 0; m < 4; ++m)
    #pragma unroll
    for (int n = 0; n < 2; ++n) {
      int col = col0 + wc * 32 + n * 16 + lr;
      float bb = (col < 512) ? bq[col] : (col < 1024) ? bk[col - 512] : bv[col - 1024];
      #pragma unroll
      for (int r = 0; r < 4; ++r) {
        int row = row0 + wr * 64 + m * 16 + lkq * 4 + r;
        float val = acch[m][n][r] + accl[m][n][r] * LO_SCALE + bb;
        f16 vh = (f16)val;
        f16 vl = (f16)((val - (float)vh) * 4096.0f);
        qkvh[(size_t)row * 1536 + col] = (u32)f16b(vh) | ((u32)f16b(vl) << 16);
      }
    }
}

__global__ __launch_bounds__(512, 2) void qkv_gemm_kernel(
    const u16* __restrict__ hh, const u16* __restrict__ hl,
    const u16* __restrict__ whi, const u16* __restrict__ wlo,
    const float* __restrict__ bq, const float* __restrict__ bk,
    const float* __restrict__ bv, u32* __restrict__ qkvh, int M0)
{
  __shared__ alignas(16) u16 SM[2][16384];
  qkv_body(blockIdx.x + 12 * blockIdx.y, &SM[0][0],
           hh, hl, whi, wlo, bq, bk, bv, qkvh, M0);
}

// ---------------------------------------------------------------------------
// wo GEMM body: clone of qkv template, M=16384 N=512 K=512, 512 blocks.
// Epilogue: dout = x + val (+bo). XCD remap: 16 row-tiles x 4 col-tiles/XCD.
__device__ __forceinline__ void wo_body(
    int lid, u16* SMb,
    const u16* __restrict__ cth, const u16* __restrict__ ctl,
    const u16* __restrict__ whi, const u16* __restrict__ wlo,
    const float* __restrict__ bo, const float* __restrict__ x,
    float* __restrict__ dout, int M0)
{
  const int tid = threadIdx.x;
  const int lane = tid & 63, w = tid >> 6;
  const int c8 = lid & 7, kk = lid >> 3;      // kk in [0,64)
  const int rt = c8 * 16 + (kk >> 2), ct = kk & 3;
  const int col0 = ct * 128;
  const int row0 = rt * 128;
  const int wr = w >> 2, wc = w & 3;
  const int lr = lane & 15, lkq = lane >> 4;
  const int sx = (lkq ^ SWZF(lr)) * 8;
  const int lrow = lane >> 2;
  const int lcs = ((lane & 3) ^ SWZF(lrow)) * 8;

  const u16* wh3 = whi + 3 * 262144;
  const u16* wl3 = wlo + 3 * 262144;

  const u16* gsrc[4];
  int loff[4];
  #pragma unroll
  for (int j = 0; j < 4; ++j) {
    const int q = w * 4 + j;
    loff[j] = q * 512;
    if (q < 8)       gsrc[j] = cth + (size_t)(row0 + q * 16 + lrow) * 512 + lcs;
    else if (q < 16) gsrc[j] = ctl + (size_t)(row0 + (q - 8) * 16 + lrow) * 512 + lcs;
    else if (q < 24) gsrc[j] = wh3 + (size_t)(col0 + (q - 16) * 16 + lrow) * 512 + lcs;
    else             gsrc[j] = wl3 + (size_t)(col0 + (q - 24) * 16 + lrow) * 512 + lcs;
  }

  f32x4 acch[4][2], accl[4][2];
  #pragma unroll
  for (int m = 0; m < 4; ++m)
    #pragma unroll
    for (int n = 0; n < 2; ++n) {
      f32x4 zz = {0.f, 0.f, 0.f, 0.f};
      acch[m][n] = zz; accl[m][n] = zz;
    }

  #pragma unroll
  for (int j = 0; j < 4; ++j) gl16(gsrc[j], &SMb[loff[j]]);
  #pragma unroll
  for (int j = 0; j < 4; ++j) gl16(gsrc[j] + 32, &SMb[16384 + loff[j]]);

  for (int kc = 0; kc < 16; ++kc) {
    if (kc == 15) asm volatile("s_waitcnt vmcnt(0)" ::: "memory");
    else          asm volatile("s_waitcnt vmcnt(4)" ::: "memory");
    __builtin_amdgcn_s_barrier();
    __builtin_amdgcn_sched_barrier(0);
    const u16* S = &SMb[(kc & 1) * 16384];
    f16x8 ah[4], al[4], bh[2], bl[2];
    #pragma unroll
    for (int m = 0; m < 4; ++m) {
      int r = wr * 64 + m * 16 + lr;
      ah[m] = *(const f16x8*)&S[r * 32 + sx];
      al[m] = *(const f16x8*)&S[4096 + r * 32 + sx];
    }
    #pragma unroll
    for (int n = 0; n < 2; ++n) {
      int c = wc * 32 + n * 16 + lr;
      bh[n] = *(const f16x8*)&S[8192 + c * 32 + sx];
      bl[n] = *(const f16x8*)&S[12288 + c * 32 + sx];
    }
    #pragma unroll
    for (int m = 0; m < 4; ++m)
      #pragma unroll
      for (int n = 0; n < 2; ++n) {
        acch[m][n] = MFMA16(ah[m], bh[n], acch[m][n]);
        accl[m][n] = MFMA16(ah[m], bl[n], accl[m][n]);
        accl[m][n] = MFMA16(al[m], bh[n], accl[m][n]);
      }
    __builtin_amdgcn_s_barrier();
    __builtin_amdgcn_sched_barrier(0);
    if (kc + 2 < 16) {
      #pragma unroll
      for (int j = 0; j < 4; ++j) gl16(gsrc[j] + (kc + 2) * 32, &SMb[(kc & 1) * 16384 + loff[j]]);
    }
  }
  #pragma unroll
  for (int m = 0; m < 4; ++m)
    #pragma unroll
    for (int n = 0; n < 2; ++n) {
      int col = col0 + wc * 32 + n * 16 + lr;
      float bvv = bo[col];
      #pragma unroll
      for (int r = 0; r < 4; ++r) {
        int row = row0 + wr * 64 + m * 16 + lkq * 4 + r;
        float val = acch[m][n][r] + accl[m][n][r] * LO_SCALE + bvv;
        size_t gi = (size_t)(M0 + row) * 512 + col;
        dout[gi] = x[gi] + val;
      }
    }
}

__global__ __launch_bounds__(512, 2) void wo_gemm_kernel(
    const u16* __restrict__ cth, const u16* __restrict__ ctl,
    const u16* __restrict__ whi, const u16* __restrict__ wlo,
    const float* __restrict__ bo, const float* __restrict__ x,
    float* __restrict__ dout, int M0)
{
  __shared__ alignas(16) u16 SM[2][16384];
  wo_body(blockIdx.x + 4 * blockIdx.y, &SM[0][0],
          cth, ctl, whi, wlo, bo, x, dout, M0);
}

// ---------------------------------------------------------------------------
// Attention only (per quarter): 32 tokens (2 seqs) per block, 8 waves.
__global__ __launch_bounds__(512) void attn_kernel(
    const u32* __restrict__ qkvh, u16* __restrict__ cth, u16* __restrict__ ctl)
{
  __shared__ alignas(16) u32 vS[16384];        // 64KB: packed V
  __shared__ float pS[8][16][17];

  const int tid = threadIdx.x;
  const int lane = tid & 63, w = tid >> 6;
  const int lr = lane & 15, lkq = lane >> 4;
  const int row0 = blockIdx.x * 32;

  #pragma unroll
  for (int i = 0; i < 8; ++i) {
    int chunk = w * 8 + i;
    const u32* src = qkvh + (size_t)(row0 + (chunk >> 1)) * 1536 + 1024 + (chunk & 1) * 256 + lane * 4;
    gl16((const u16*)src, (u16*)(vS + chunk * 256));
  }
  __syncthreads();

  const int h4 = w & 3, s = w >> 2;
  #pragma unroll
  for (int g = 0; g < 2; ++g) {
    const int h = g * 4 + h4;
    f16x8 qh[2], ql[2], kh[2], kl[2];
    #pragma unroll
    for (int dc = 0; dc < 2; ++dc) {
      const u32* qp = qkvh + (size_t)(row0 + s * 16 + lr) * 1536 + h * 64 + dc * 32 + lkq * 8;
      const u32* kp = qp + 512;
      uint4 q0 = *(const uint4*)qp, q1 = *(const uint4*)(qp + 4);
      uint4 k0 = *(const uint4*)kp, k1 = *(const uint4*)(kp + 4);
      u32 qu[8] = {q0.x, q0.y, q0.z, q0.w, q1.x, q1.y, q1.z, q1.w};
      u32 ku[8] = {k0.x, k0.y, k0.z, k0.w, k1.x, k1.y, k1.z, k1.w};
      #pragma unroll
      for (int i = 0; i < 8; ++i) {
        qh[dc][i] = b2h((u16)(qu[i] & 0xffffu)); ql[dc][i] = b2h((u16)(qu[i] >> 16));
        kh[dc][i] = b2h((u16)(ku[i] & 0xffffu)); kl[dc][i] = b2h((u16)(ku[i] >> 16));
      }
    }
    f32x4 sh = {0.f, 0.f, 0.f, 0.f}, sl = {0.f, 0.f, 0.f, 0.f};
    #pragma unroll
    for (int dc = 0; dc < 2; ++dc) {
      sh = MFMA16(qh[dc], kh[dc], sh);
      sl = MFMA16(qh[dc], kl[dc], sl);
      sl = MFMA16(ql[dc], kh[dc], sl);
    }
    float p_[4];
    #pragma unroll
    for (int r = 0; r < 4; ++r) {
      float sv = (sh[r] + sl[r] * LO_SCALE) * 0.125f;
      float mx = sv;
      #pragma unroll
      for (int off = 8; off; off >>= 1) mx = fmaxf(mx, __shfl_xor(mx, off, 16));
      float e = expf(sv - mx);
      float su = e;
      #pragma unroll
      for (int off = 8; off; off >>= 1) su += __shfl_xor(su, off, 16);
      p_[r] = e / su;
    }
    #pragma unroll
    for (int r = 0; r < 4; ++r) pS[w][lkq * 4 + r][lr] = p_[r];
    f16x8 pah, pal;
    #pragma unroll
    for (int jj = 0; jj < 8; ++jj) {
      float pv = (lkq < 2) ? pS[w][lr][lkq * 8 + jj] : 0.0f;
      f16 ph = (f16)pv;
      pah[jj] = ph;
      pal[jj] = (f16)((pv - (float)ph) * 4096.0f);
    }
    #pragma unroll
    for (int cf = 0; cf < 4; ++cf) {
      f16x8 vhf, vlf;
      #pragma unroll
      for (int jj = 0; jj < 8; ++jj) {
        u32 u = (lkq < 2) ? vS[(size_t)(s * 16 + lkq * 8 + jj) * 512 + h * 64 + cf * 16 + lr] : 0u;
        vhf[jj] = b2h((u16)(u & 0xffffu));
        vlf[jj] = b2h((u16)(u >> 16));
      }
      f32x4 ch = {0.f, 0.f, 0.f, 0.f}, cl = {0.f, 0.f, 0.f, 0.f};
      ch = MFMA16(pah, vhf, ch);
      cl = MFMA16(pah, vlf, cl);
      cl = MFMA16(pal, vhf, cl);
      #pragma unroll
      for (int r = 0; r < 4; ++r) {
        float cv = ch[r] + cl[r] * LO_SCALE;
        int row = row0 + s * 16 + lkq * 4 + r;
        int d = h * 64 + cf * 16 + lr;
        size_t gi = (size_t)row * 512 + d;
        f16 chv = (f16)cv;
        cth[gi] = f16b(chv);
        ctl[gi] = f16b((f16)((cv - (float)chv) * 4096.0f));
      }
    }
  }
}

// ---------------------------------------------------------------------------
// Router (reads dout = post-attn residual): one wave per token, no LDS.
// Also writes xn[tok] = bf16 LN2(dout[tok]) (gather fused away).
__global__ __launch_bounds__(256) void router_kernel(
    const float* __restrict__ xp, const float* __restrict__ g2,
    const float* __restrict__ b2ln, const float* __restrict__ rwt,
    const float* __restrict__ rb, float* __restrict__ stats,
    int* __restrict__ t2, u16* __restrict__ xn)
{
  const int tid = threadIdx.x;
  const int lane = tid & 63, w = tid >> 6;
  const int tok = blockIdx.x * 4 + w;
  const float* xr = xp + (size_t)tok * 512 + lane * 8;
  float4 a = *(const float4*)(xr);
  float4 b = *(const float4*)(xr + 4);
  double s1 = (double)a.x + a.y + a.z + a.w + b.x + b.y + b.z + b.w;
  double s2 = (double)a.x * a.x + (double)a.y * a.y + (double)a.z * a.z + (double)a.w * a.w
            + (double)b.x * b.x + (double)b.y * b.y + (double)b.z * b.z + (double)b.w * b.w;
  #pragma unroll
  for (int off = 32; off; off >>= 1) {
    s1 += __shfl_xor(s1, off, 64);
    s2 += __shfl_xor(s2, off, 64);
  }
  double mu = s1 * (1.0 / 512.0);
  double var = s2 * (1.0 / 512.0) - mu * mu;
  double rs = 1.0 / sqrt(var + 1e-5);
  if (lane == 0) {
    stats[tok * 2] = (float)mu;
    stats[tok * 2 + 1] = (float)rs;
  }
  float4 ga = *(const float4*)(g2 + lane * 8);
  float4 gb = *(const float4*)(g2 + lane * 8 + 4);
  float4 ca = *(const float4*)(b2ln + lane * 8);
  float4 cb = *(const float4*)(b2ln + lane * 8 + 4);
  // --- xn write: EXACT replica of old gather's f32 math (f32 mu/rs) ---
  {
    float muf = (float)mu, rsf = (float)rs;
    u16 ox[8];
    ox[0] = f2bf((a.x - muf) * rsf * ga.x + ca.x);
    ox[1] = f2bf((a.y - muf) * rsf * ga.y + ca.y);
    ox[2] = f2bf((a.z - muf) * rsf * ga.z + ca.z);
    ox[3] = f2bf((a.w - muf) * rsf * ga.w + ca.w);
    ox[4] = f2bf((b.x - muf) * rsf * gb.x + cb.x);
    ox[5] = f2bf((b.y - muf) * rsf * gb.y + cb.y);
    ox[6] = f2bf((b.z - muf) * rsf * gb.z + cb.z);
    ox[7] = f2bf((b.w - muf) * rsf * gb.w + cb.w);
    *(short8*)(xn + (size_t)tok * 512 + lane * 8) = *(const short8*)ox;
  }
  float h[8];
  h[0] = (float)(((double)a.x - mu) * rs * (double)ga.x + (double)ca.x);
  h[1] = (float)(((double)a.y - mu) * rs * (double)ga.y + (double)ca.y);
  h[2] = (float)(((double)a.z - mu) * rs * (double)ga.z + (double)ca.z);
  h[3] = (float)(((double)a.w - mu) * rs * (double)ga.w + (double)ca.w);
  h[4] = (float)(((double)b.x - mu) * rs * (double)gb.x + (double)cb.x);
  h[5] = (float)(((double)b.y - mu) * rs * (double)gb.y + (double)cb.y);
  h[6] = (float)(((double)b.z - mu) * rs * (double)gb.z + (double)cb.z);
  h[7] = (float)(((double)b.w - mu) * rs * (double)gb.w + (double)cb.w);
  double acc[8];
  #pragma unroll
  for (int e = 0; e < 8; ++e) {
    const float* wp = rwt + e * 512 + lane * 8;
    float4 w0 = *(const float4*)wp;
    float4 w1 = *(const float4*)(wp + 4);
    acc[e] = (double)h[0] * (double)w0.x + (double)h[1] * (double)w0.y
           + (double)h[2] * (double)w0.z + (double)h[3] * (double)w0.w
           + (double)h[4] * (double)w1.x + (double)h[5] * (double)w1.y
           + (double)h[6] * (double)w1.z + (double)h[7] * (double)w1.w;
  }
  #pragma unroll
  for (int e = 0; e < 8; ++e) {
    acc[e] += __shfl_xor(acc[e], 8, 64);
    acc[e] += __shfl_xor(acc[e], 16, 64);
    acc[e] += __shfl_xor(acc[e], 32, 64);
  }
  const int b0 = lane & 1, b1 = (lane >> 1) & 1, b2_ = (lane >> 2) & 1;
  double t4[4];
  #pragma unroll
  for (int k = 0; k < 4; ++k) {
    double mine = b0 ? acc[2 * k + 1] : acc[2 * k];
    double send = b0 ? acc[2 * k] : acc[2 * k + 1];
    t4[k] = mine + __shfl_xor(send, 1, 64);
  }
  double u2[2];
  #pragma unroll
  for (int k = 0; k < 2; ++k) {
    double mine = b1 ? t4[2 * k + 1] : t4[2 * k];
    double send = b1 ? t4[2 * k] : t4[2 * k + 1];
    u2[k] = mine + __shfl_xor(send, 2, 64);
  }
  {
    double mine = b2_ ? u2[1] : u2[0];
    double send = b2_ ? u2[0] : u2[1];
    double tot = mine + __shfl_xor(send, 4, 64);
    const int e = lane & 7;
    double lg = tot + (double)rb[e];
    double vv = lg; int ix = e;
    #pragma unroll
    for (int off = 4; off; off >>= 1) {
      double ov = __shfl_xor(vv, off, 8);
      int oi = __shfl_xor(ix, off, 8);
      if (ov > vv || (ov == vv && oi < ix)) { vv = ov; ix = oi; }
    }
    double v2 = (e == ix) ? -1.0e300 : lg; int ix2 = e;
    #pragma unroll
    for (int off = 4; off; off >>= 1) {
      double ov = __shfl_xor(v2, off, 8);
      int oi = __shfl_xor(ix2, off, 8);
      if (ov > v2 || (ov == v2 && oi < ix2)) { v2 = ov; ix2 = oi; }
    }
    if (lane == 0) t2[tok] = ix | (ix2 << 8);
  }
}

// ---------------------------------------------------------------------------
// Routing scans (all deterministic, zero atomics).
__global__ __launch_bounds__(256) void scan1_kernel(
    const int* __restrict__ t2, int* __restrict__ blkcnt, int* __restrict__ ranks)
{
  __shared__ u32 mask[256];
  __shared__ u16 rk[256][8];
  const int t = threadIdx.x, tok = blockIdx.x * 256 + t;
  const int p = t2[tok];
  const int e1 = p & 0xff, e2 = (p >> 8) & 0xff;
  mask[t] = (1u << e1) | (1u << e2);
  __syncthreads();
  if (t < 8) {
    int c = 0;
    for (int i = 0; i < 256; ++i) { rk[i][t] = (u16)c; c += (mask[i] >> t) & 1u; }
    blkcnt[blockIdx.x * 8 + t] = c;
  }
  __syncthreads();
  ranks[tok] = (int)rk[t][e1] | ((int)rk[t][e2] << 16);
}

__global__ void scan2_kernel(const int* __restrict__ blkcnt,
                             int* __restrict__ offs)
{
  const int e = threadIdx.x;
  if (e < 8) {
    int off = 0;
    for (int b = 0; b < 256; ++b) { offs[b * 8 + e] = off; off += blkcnt[b * 8 + e]; }
  }
}

// scan3: winner determination + per-block winner counts/ranks (scan1 pattern).
__global__ __launch_bounds__(256) void scan3_kernel(
    const int* __restrict__ t2, const int* __restrict__ ranks,
    const int* __restrict__ offs, int* __restrict__ wblkcnt,
    int* __restrict__ wrk_tok)
{
  __shared__ u32 wmask[256];
  __shared__ u16 wrk[256][8];
  const int t = threadIdx.x, blk = blockIdx.x, tok = blk * 256 + t;
  const int p = t2[tok];
  const int e1 = p & 0xff, e2 = (p >> 8) & 0xff;
  const int r = ranks[tok];
  const int s1 = offs[blk * 8 + e1] + (r & 0xffff);
  const int s2 = offs[blk * 8 + e2] + ((r >> 16) & 0xffff);
  int w = -1;
  if (s1 < CAP) w = (e1 > w) ? e1 : w;
  if (s2 < CAP) w = (e2 > w) ? e2 : w;
  wmask[t] = (w >= 0) ? (1u << w) : 0u;
  __syncthreads();
  if (t < 8) {
    int c = 0;
    for (int i = 0; i < 256; ++i) { wrk[i][t] = (u16)c; c += (wmask[i] >> t) & 1u; }
    wblkcnt[blk * 8 + t] = c;
  }
  __syncthreads();
  wrk_tok[tok] = (w >= 0) ? ((int)wrk[t][w] | (w << 16)) : -1;
}

// scan4: prefix-sum winner block counts -> per-block winner offsets + totals.
__global__ void scan4_kernel(const int* __restrict__ wblkcnt,
                             int* __restrict__ woffs, int* __restrict__ wcnt)
{
  const int e = threadIdx.x;
  if (e < 8) {
    int off = 0;
    for (int b = 0; b < 256; ++b) { woffs[b * 8 + e] = off; off += wblkcnt[b * 8 + e]; }
    wcnt[e] = off;
  }
}

// scan5: scatter winner tokens to compacted per-expert lists (deterministic).
__global__ __launch_bounds__(256) void scan5_kernel(
    const int* __restrict__ wrk_tok, const int* __restrict__ woffs,
    int* __restrict__ wlist)
{
  const int t = threadIdx.x, blk = blockIdx.x, tok = blk * 256 + t;
  const int pr = wrk_tok[tok];
  if (pr >= 0) {
    const int w = pr >> 16, rk = pr & 0xffff;
    wlist[w * CAPP + woffs[blk * 8 + w] + rk] = tok;
  }
}

// ---------------------------------------------------------------------------
// FFN GEMM body, 8-wave 2-RING variant: tile 128 rows x 256 cols, 512
// threads / 8 waves (2x4), wave owns 64x64 (acc 4x4); staging 3 gl16/
// thread/buffer. DOUBLE-buffered with the qkv-proven 2-barrier schedule
// (wait vmcnt(3) -> barrier -> MFMA -> barrier -> stage kc+2 into the freed
// buffer). 48KB LDS allows 3 blocks/CU = 24 waves/CU PROVIDED VGPR <= 85;
// R19's launch_bounds(512,6) forced VGPR 40 -> acc spill -> 12x scratch
// traffic. Retry with (512,4): compiler emits ~64 VGPR (R18-proven), HW
// then co-schedules 3 blocks by LDS + 8 waves/SIMD by VGPR.
// Per-output K-order and epilogue math unchanged -> bit-identical result.
// XCD remap: round-robin row-tile -> XCD (wy = (pr%13)*8 + c8). Padded
// wy==103 exits; tiles beyond the expert's winner count exit (pre-barrier).
// EPI 0 (ffn1): A = xn with per-lane winner-token indirection; GELU -> hid.
// EPI 1 (ffn2): scatter += val into dout for all rows < wcnt (all winners).
template<int EPI, int NKC, int AST, int BST, int NX>
__device__ __forceinline__ void ffn_body(
    int lid, u16* SMb,
    const u16* __restrict__ A, const u16* __restrict__ Bw,
    const float* __restrict__ bias, u16* __restrict__ outb,
    const int* __restrict__ list, const int* __restrict__ cnts,
    float* __restrict__ dout, int ebase)
{
  const int c8 = lid & 7;
  const int kk = lid >> 3;              // [0, NX*26)
  const int wx = kk & (NX - 1);
  const int pr = kk / NX;               // [0, 26)
  const int wz = pr / 13;
  const int wy = (pr % 13) * 8 + c8;    // round-robin row-tile -> XCD
  if (wy >= 103) return;                // padded tile (uniform exit, pre-barrier)
  const int ez = wz;
  const int expert = ebase + ez;
  const int cnt = cnts[expert];
  const int row0 = wy * 128;
  if (row0 >= cnt) return;              // winner-compacted tail (uniform exit)
  const int tid = threadIdx.x;
  const int lane = tid & 63, w = tid >> 6;   // 8 waves
  const int wr = w >> 2, wc = w & 3;         // wave tile: 64 rows x 64 cols
  const int colb = wx * 256;
  const int lr = lane & 15, lkq = lane >> 4;
  const int sx = (lkq ^ SWZF(lr)) * 8;
  const int lrow = lane >> 2;
  const int lcs = ((lane & 3) ^ SWZF(lrow)) * 8;

  const u16* Bp = Bw + (size_t)expert * 1048576;

  // staging: 24 chunks (A 8 + B 16) over 8 waves = 3 chunks/wave
  const u16* gsrc[3];
  int loff[3];
  #pragma unroll
  for (int j = 0; j < 3; ++j) {
    const int c = w * 3 + j;             // 0..23 (wave-uniform)
    if (c < 8) {
      const int q = c;
      int arow = row0 + q * 16 + lrow;
      if (EPI == 0) {
        int tok = list[(size_t)expert * CAPP + arow] & 65535;
        gsrc[j] = A + (size_t)tok * 512 + lcs;
      } else {
        gsrc[j] = A + (size_t)ez * CAPP * 2048 + (size_t)arow * AST + lcs;
      }
      loff[j] = q * 512;
    } else {
      const int q = c - 8;
      gsrc[j] = Bp + (size_t)(colb + q * 16 + lrow) * BST + lcs;
      loff[j] = 4096 + q * 512;
    }
  }

  f32x4 acc[4][4];
  #pragma unroll
  for (int m = 0; m < 4; ++m)
    #pragma unroll
    for (int n = 0; n < 4; ++n) {
      f32x4 zz = {0.f, 0.f, 0.f, 0.f};
      acc[m][n] = zz;
    }

  #pragma unroll
  for (int j = 0; j < 3; ++j) gl16(gsrc[j], &SMb[loff[j]]);
  #pragma unroll
  for (int j = 0; j < 3; ++j) gl16(gsrc[j] + 32, &SMb[12288 + loff[j]]);

  for (int kc = 0; kc < NKC; ++kc) {
    if (kc == NKC - 1) asm volatile("s_waitcnt vmcnt(0)" ::: "memory");
    else               asm volatile("s_waitcnt vmcnt(3)" ::: "memory");
    __builtin_amdgcn_s_barrier();
    __builtin_amdgcn_sched_barrier(0);
    const u16* S = &SMb[(kc & 1) * 12288];
    short8 af[4], bf[4];
    #pragma unroll
    for (int m = 0; m < 4; ++m)
      af[m] = *(const short8*)&S[(wr * 64 + m * 16 + lr) * 32 + sx];
    #pragma unroll
    for (int n = 0; n < 4; ++n)
      bf[n] = *(const short8*)&S[4096 + (wc * 64 + n * 16 + lr) * 32 + sx];
    #pragma unroll
    for (int m = 0; m < 4; ++m)
      #pragma unroll
      for (int n = 0; n < 4; ++n)
        acc[m][n] = MFMAB(af[m], bf[n], acc[m][n]);
    __builtin_amdgcn_s_barrier();
    __builtin_amdgcn_sched_barrier(0);
    if (kc + 2 < NKC) {
      #pragma unroll
      for (int j = 0; j < 3; ++j) gl16(gsrc[j] + (kc + 2) * 32, &SMb[(kc & 1) * 12288 + loff[j]]);
    }
  }

  if (EPI == 0) {
    #pragma unroll
    for (int m = 0; m < 4; ++m)
      #pragma unroll
      for (int n = 0; n < 4; ++n) {
        int col = colb + wc * 64 + n * 16 + lr;
        float bvv = bias[expert * 2048 + col];
        #pragma unroll
        for (int r = 0; r < 4; ++r) {
          int row = row0 + wr * 64 + m * 16 + lkq * 4 + r;
          float val = acc[m][n][r] + bvv;
          outb[(size_t)ez * CAPP * 2048 + (size_t)row * 2048 + col] = f2bf(gelu_f(val));
        }
      }
  } else {
    const int* gidx = list + (size_t)expert * CAPP;
    #pragma unroll
    for (int m = 0; m < 4; ++m) {
      int rowb = row0 + wr * 64 + m * 16 + lkq * 4;
      #pragma unroll
      for (int r = 0; r < 4; ++r) {
        int row = rowb + r;
        if (row < cnt) {
          int tok = gidx[row];
          #pragma unroll
          for (int n = 0; n < 4; ++n) {
            int col = colb + wc * 64 + n * 16 + lr;
            float val = acc[m][n][r] + bias[expert * 512 + col];
            size_t oi = (size_t)tok * 512 + col;
            dout[oi] = dout[oi] + val;   // dout holds x2; same-thread RMW
          }
        }
      }
    }
  }
}

// Merged dispatch: role-2 (ffn2 of previous expert pair, long 64-step blocks)
// occupies bx < nb2 so it launches FIRST; role-1 (ffn1 of current pair) fills
// the remaining CU slots around it.
__global__ __launch_bounds__(512, 4) void ffn_merged_kernel(
    const u16* __restrict__ xn, const u16* __restrict__ w1t,
    const float* __restrict__ b1, u16* __restrict__ hidW,
    const u16* __restrict__ hidR, const u16* __restrict__ w2t,
    const float* __restrict__ b2,
    const int* __restrict__ wlist, const int* __restrict__ wcnt,
    float* __restrict__ dout, int nb2, int eb1, int eb2)
{
  __shared__ alignas(16) u16 SM[2][12288];   // 48KB -> 3 blocks/CU possible
  const int bx = blockIdx.x;
  if (bx < nb2) {
    ffn_body<1, 64, 2048, 2048, 2>(bx, &SM[0][0], hidR, w2t, b2, nullptr,
                                   wlist, wcnt, dout, eb2);
  } else {
    ffn_body<0, 16, 512, 512, 8>(bx - nb2, &SM[0][0], xn, w1t, b1, hidW,
                                 wlist, wcnt, nullptr, eb1);
  }
}

// ---------------------------------------------------------------------------
extern "C" void kernel_launch(void* const* d_in, const int* in_sizes, int n_in,
                              void* d_out, int out_size, void* d_ws, size_t ws_size,
                              hipStream_t stream) {
  const float* x    = (const float*)d_in[0];
  const float* ln1g = (const float*)d_in[1];
  const float* ln1b = (const float*)d_in[2];
  const float* ln2g = (const float*)d_in[3];
  const float* ln2b = (const float*)d_in[4];
  const float* wq   = (const float*)d_in[5];
  const float* bq   = (const float*)d_in[6];
  const float* wk   = (const float*)d_in[7];
  const float* bk   = (const float*)d_in[8];
  const float* wv   = (const float*)d_in[9];
  const float* bv   = (const float*)d_in[10];
  const float* wo   = (const float*)d_in[11];
  const float* bo   = (const float*)d_in[12];
  const float* rw   = (const float*)d_in[13];
  const float* rb   = (const float*)d_in[14];
  const float* w1   = (const float*)d_in[15];
  const float* b1   = (const float*)d_in[16];
  const float* w2   = (const float*)d_in[17];
  const float* b2   = (const float*)d_in[18];
  float* dout = (float*)d_out;

  char* ws = (char*)d_ws;
  u16*   hh   = (u16*)(ws + 0LL);            // [65536][512] f16 hi
  u16*   hl   = (u16*)(ws + 67108864LL);     // lo plane
  u32*   qkvh = (u32*)(ws + 134217728LL);    // [16384][1536] packed quarter
  u16*   cth  = (u16*)(ws + 234881024LL);    // ctx hi quarter (dead before router)
  u16*   ctl  = (u16*)(ws + 251658240LL);    // ctx lo quarter
  u16*   whi  = (u16*)(ws + 369098752LL);
  u16*   wlo  = (u16*)(ws + 371195904LL);
  float* rwt  = (float*)(ws + 373293056LL);
  float* st2  = (float*)(ws + 373309440LL);
  int*   t2   = (int*)(ws + 373833728LL);
  int*   rks  = (int*)(ws + 374095872LL);
  int*   bc   = (int*)(ws + 374358016LL);
  int*   offs = (int*)(ws + 374366208LL);
  int*   wcnt = (int*)(ws + 374374400LL);    // 8 winner counts
  int*   wlst = (int*)(ws + 374374464LL);    // [8][CAPP] winner token lists
  int*   wrkt = (int*)(ws + 374796352LL);    // [65536] packed (winner, rank)
  int*   wbc  = (int*)(ws + 375058496LL);    // [256][8] winner block counts
  int*   wofs = (int*)(ws + 375066688LL);    // [256][8] winner block offsets
  // aliases (regions dead by the time these are written)
  u16*   w1t  = (u16*)(ws + 0LL);            // in hh (dead after qkv q3)
  u16*   w2t  = (u16*)(ws + 16777216LL);     // in hh
  u16*   xn   = (u16*)(ws + 33554432LL);     // [65536][512] bf16 (32..96MB; hh/hl dead)
  u16*   hid0 = (u16*)(ws + 100663296LL);    // 2 experts x CAPP x 2048 bf16 (103MB)
  u16*   hid1 = (u16*)(ws + 208666624LL);    // second buffer (ends ~302MB < whi)

  prep1_kernel<<<dim3(1024, 1, 5), 256, 0, stream>>>(wq, wk, wv, wo, rw, whi, wlo, rwt);
  ln1_kernel<<<16384, 256, 0, stream>>>(x, ln1g, ln1b, hh, hl);
  for (int q = 0; q < 4; ++q) {
    qkv_gemm_kernel<<<dim3(12, 128), 512, 0, stream>>>(
        hh, hl, whi, wlo, bq, bk, bv, qkvh, q * QTOK);
    attn_kernel<<<512, 512, 0, stream>>>(qkvh, cth, ctl);
    wo_gemm_kernel<<<dim3(4, 128), 512, 0, stream>>>(
        cth, ctl, whi, wlo, bo, x, dout, q * QTOK);
  }
  prep2_kernel<<<dim3(256, 1, 16), 256, 0, stream>>>(w1, w2, w1t, w2t);
  router_kernel<<<16384, 256, 0, stream>>>(dout, ln2g, ln2b, rwt, rb, st2, t2, xn);
  scan1_kernel<<<256, 256, 0, stream>>>(t2, bc, rks);
  scan2_kernel<<<1, 256, 0, stream>>>(bc, offs);
  scan3_kernel<<<256, 256, 0, stream>>>(t2, rks, offs, wbc, wrkt);
  scan4_kernel<<<1, 256, 0, stream>>>(wbc, wofs, wcnt);
  scan5_kernel<<<256, 256, 0, stream>>>(wrkt, wofs, wlst);
  // 5-stage software pipeline: stage s runs ffn1(experts 2s,2s+1) into
  // hid[s&1] concurrently with ffn2(experts 2s-2,2s-1) from hid[(s-1)&1].
  // Winner-compacted: tiles beyond each expert's winner count early-exit;
  // round-robin row-tile->XCD mapping keeps the active prefix balanced.
  // 8-wave 2-ring blocks (48KB LDS): up to 3 blocks/CU at ~64 VGPR.
  for (int s = 0; s < 5; ++s) {
    const int nb1 = (s < 4) ? 1664 : 0;   // 8*104*2 (incl. padded tiles)
    const int nb2 = (s > 0) ? 416 : 0;    // 2*104*2
    u16* hw = (s & 1) ? hid1 : hid0;
    const u16* hr = ((s - 1) & 1) ? hid1 : hid0;
    ffn_merged_kernel<<<nb1 + nb2, 512, 0, stream>>>(
        xn, w1t, b1, hw, hr, w2t, b2, wlst, wcnt, dout,
        nb2, s * 2, (s - 1) * 2);
  }
}

// Round 21
// 1157.863 us; speedup vs baseline: 2.6546x; 1.0091x over previous
//
#include <hip/hip_runtime.h>
#include <hip/hip_bf16.h>
#include <math.h>

typedef unsigned short u16;
typedef unsigned int u32;
typedef _Float16 f16;
typedef __attribute__((ext_vector_type(8))) _Float16 f16x8;
typedef __attribute__((ext_vector_type(8))) short short8;
typedef __attribute__((ext_vector_type(4))) float f32x4;

#define TTOK 65536
#define QTOK 16384
#define CAP 13108
#define CAPP 13184  // 103*128

#define MFMA16(a, b, c) __builtin_amdgcn_mfma_f32_16x16x32_f16(a, b, c, 0, 0, 0)
#define MFMAB(a, b, c) __builtin_amdgcn_mfma_f32_16x16x32_bf16(a, b, c, 0, 0, 0)
#define LO_SCALE 2.44140625e-4f  // 2^-12

// 3-bit XOR swizzle: slot s of row r holds col-seg s ^ F(r).
#define SWZF(r) (((r) & 3) ^ ((((r) >> 2) & 1) << 1))

__device__ __forceinline__ u16 f2bf(float f) {
  union { float f; u32 u; } v; v.f = f;
  u32 r = v.u + 0x7fffu + ((v.u >> 16) & 1u);
  return (u16)(r >> 16);
}
__device__ __forceinline__ u16 f16b(f16 h) {
  union { f16 h; u16 u; } v; v.h = h; return v.u;
}
__device__ __forceinline__ f16 b2h(u16 u) {
  union { u16 s; f16 h; } v; v.s = u; return v.h;
}
// Fast exact GELU: A&S 7.1.26 erf, |err|<=1.5e-7 (far below bf16 noise).
__device__ __forceinline__ float gelu_f(float x) {
  float z = fabsf(x) * 0.70710678118654752f;
  float t = __builtin_amdgcn_rcpf(1.0f + 0.3275911f * z);
  float p = t * (0.254829592f + t * (-0.284496736f + t * (1.421413741f
          + t * (-1.453152027f + t * 1.061405429f))));
  float er = 1.0f - p * __expf(-z * z);
  er = (x < 0.0f) ? -er : er;
  return 0.5f * x * (1.0f + er);
}
// async global->LDS, 16B per lane; dest = wave-uniform base + lane*16
__device__ __forceinline__ void gl16(const u16* g, u16* l) {
  __builtin_amdgcn_global_load_lds(
      (const __attribute__((address_space(1))) u32*)(const void*)g,
      (__attribute__((address_space(3))) u32*)(void*)l, 16, 0, 0);
}

// ---------------------------------------------------------------------------
// prep1: wq/wk/wv/wo [K=512][N=512] f32 -> f16 hi/lo planes [2048][512];
// router_w -> rwt [8][512] f32.
__global__ __launch_bounds__(256) void prep1_kernel(
    const float* __restrict__ wq, const float* __restrict__ wk,
    const float* __restrict__ wv, const float* __restrict__ wo,
    const float* __restrict__ rw,
    u16* __restrict__ whi, u16* __restrict__ wlo, float* __restrict__ rwt)
{
  const int z = blockIdx.z;
  int idx = blockIdx.x * 256 + threadIdx.x;
  if (z == 4) {
    if (idx < 4096) {
      int n = idx >> 9, k = idx & 511;
      rwt[idx] = rw[k * 8 + n];
    }
    return;
  }
  const float* src = (z == 0) ? wq : (z == 1) ? wk : (z == 2) ? wv : wo;
  int n = idx >> 9, k = idx & 511;
  float v = src[k * 512 + n];
  f16 h = (f16)v;
  f16 l = (f16)((v - (float)h) * 4096.0f);
  whi[z * 262144 + idx] = f16b(h);
  wlo[z * 262144 + idx] = f16b(l);
}

// ---------------------------------------------------------------------------
// prep2: LDS-tiled transpose to bf16.
__global__ __launch_bounds__(256) void prep2_kernel(
    const float* __restrict__ w1, const float* __restrict__ w2,
    u16* __restrict__ w1t, u16* __restrict__ w2t)
{
  __shared__ float tS[64][65];
  const int z = blockIdx.z;
  const float* src; u16* dst; int R, C;
  if (z < 8) { src = w1 + (size_t)z * 1048576; dst = w1t + (size_t)z * 1048576; R = 512; C = 2048; }
  else       { src = w2 + (size_t)(z - 8) * 1048576; dst = w2t + (size_t)(z - 8) * 1048576; R = 2048; C = 512; }
  const int tc = C >> 6;
  const int r0 = (blockIdx.x / tc) * 64, c0 = (blockIdx.x % tc) * 64;
  const int tid = threadIdx.x;
  #pragma unroll
  for (int j = 0; j < 16; ++j) {
    int idx = j * 256 + tid;
    int r = idx >> 6, c = idx & 63;
    tS[r][c] = src[(size_t)(r0 + r) * C + c0 + c];
  }
  __syncthreads();
  #pragma unroll
  for (int j = 0; j < 16; ++j) {
    int idx = j * 256 + tid;
    int c = idx >> 6, r = idx & 63;
    dst[(size_t)(c0 + c) * R + r0 + r] = f2bf(tS[r][c]);
  }
}

// ---------------------------------------------------------------------------
// LN1: one wave per row (4 rows/block). f64 stats via shfl_xor butterfly.
__global__ __launch_bounds__(256) void ln1_kernel(
    const float* __restrict__ x, const float* __restrict__ g,
    const float* __restrict__ b, u16* __restrict__ hh, u16* __restrict__ hl)
{
  const int row = blockIdx.x * 4 + (threadIdx.x >> 6);
  const int lane = threadIdx.x & 63;
  const float* xr = x + (size_t)row * 512 + lane * 8;
  float4 a = *(const float4*)xr;
  float4 c = *(const float4*)(xr + 4);
  double s1 = (double)a.x + a.y + a.z + a.w + c.x + c.y + c.z + c.w;
  double s2 = (double)a.x * a.x + (double)a.y * a.y + (double)a.z * a.z + (double)a.w * a.w
            + (double)c.x * c.x + (double)c.y * c.y + (double)c.z * c.z + (double)c.w * c.w;
  #pragma unroll
  for (int off = 32; off; off >>= 1) {
    s1 += __shfl_xor(s1, off, 64);
    s2 += __shfl_xor(s2, off, 64);
  }
  double mu = s1 * (1.0 / 512.0);
  double var = s2 * (1.0 / 512.0) - mu * mu;
  double rs = 1.0 / sqrt(var + 1e-5);
  float4 ga = *(const float4*)(g + lane * 8);
  float4 gb = *(const float4*)(g + lane * 8 + 4);
  float4 ba = *(const float4*)(b + lane * 8);
  float4 bb = *(const float4*)(b + lane * 8 + 4);
  float vv[8] = {a.x, a.y, a.z, a.w, c.x, c.y, c.z, c.w};
  float gg[8] = {ga.x, ga.y, ga.z, ga.w, gb.x, gb.y, gb.z, gb.w};
  float cc[8] = {ba.x, ba.y, ba.z, ba.w, bb.x, bb.y, bb.z, bb.w};
  u16 oh[8], ol[8];
  #pragma unroll
  for (int j = 0; j < 8; ++j) {
    float t = (float)(((double)vv[j] - mu) * rs);
    float n0 = t * gg[j] + cc[j];
    f16 h = (f16)n0;
    oh[j] = f16b(h);
    ol[j] = f16b((f16)((n0 - (float)h) * 4096.0f));
  }
  size_t base = (size_t)row * 512 + lane * 8;
  *(short8*)(hh + base) = *(const short8*)oh;
  *(short8*)(hl + base) = *(const short8*)ol;
}

// ---------------------------------------------------------------------------
// QKV GEMM body: 8 waves, tile 128x128, split-f16 3-MFMA, 2-phase
// double-buffered global_load_lds with counted vmcnt. Output packed hi|lo u32.
// XCD remap (T1): XCD c owns 16 row-tiles; its 12 col-tiles run back-to-back.
__device__ __forceinline__ void qkv_body(
    int lid, u16* SMb,
    const u16* __restrict__ hh, const u16* __restrict__ hl,
    const u16* __restrict__ whi, const u16* __restrict__ wlo,
    const float* __restrict__ bq, const float* __restrict__ bk,
    const float* __restrict__ bv, u32* __restrict__ qkvh, int M0)
{
  const int tid = threadIdx.x;
  const int lane = tid & 63, w = tid >> 6;
  const int c8 = lid & 7, kk = lid >> 3;      // kk in [0,192)
  const int rt = c8 * 16 + kk / 12;           // row-tile [16c, 16c+16)
  const int ct = kk % 12;
  const int col0 = ct * 128;
  const int row0 = rt * 128;
  const int wr = w >> 2, wc = w & 3;          // wave tile 64r x 32c
  const int lr = lane & 15, lkq = lane >> 4;
  const int sx = (lkq ^ SWZF(lr)) * 8;
  const int lrow = lane >> 2;
  const int lcs = ((lane & 3) ^ SWZF(lrow)) * 8;

  const u16* gsrc[4];
  int loff[4];
  #pragma unroll
  for (int j = 0; j < 4; ++j) {
    const int q = w * 4 + j;
    loff[j] = q * 512;
    if (q < 8)       gsrc[j] = hh + (size_t)(M0 + row0 + q * 16 + lrow) * 512 + lcs;
    else if (q < 16) gsrc[j] = hl + (size_t)(M0 + row0 + (q - 8) * 16 + lrow) * 512 + lcs;
    else if (q < 24) gsrc[j] = whi + (size_t)(col0 + (q - 16) * 16 + lrow) * 512 + lcs;
    else             gsrc[j] = wlo + (size_t)(col0 + (q - 24) * 16 + lrow) * 512 + lcs;
  }

  f32x4 acch[4][2], accl[4][2];
  #pragma unroll
  for (int m = 0; m < 4; ++m)
    #pragma unroll
    for (int n = 0; n < 2; ++n) {
      f32x4 zz = {0.f, 0.f, 0.f, 0.f};
      acch[m][n] = zz; accl[m][n] = zz;
    }

  #pragma unroll
  for (int j = 0; j < 4; ++j) gl16(gsrc[j], &SMb[loff[j]]);
  #pragma unroll
  for (int j = 0; j < 4; ++j) gl16(gsrc[j] + 32, &SMb[16384 + loff[j]]);

  for (int kc = 0; kc < 16; ++kc) {
    if (kc == 15) asm volatile("s_waitcnt vmcnt(0)" ::: "memory");
    else          asm volatile("s_waitcnt vmcnt(4)" ::: "memory");
    __builtin_amdgcn_s_barrier();
    __builtin_amdgcn_sched_barrier(0);
    const u16* S = &SMb[(kc & 1) * 16384];
    f16x8 ah[4], al[4], bh[2], bl[2];
    #pragma unroll
    for (int m = 0; m < 4; ++m) {
      int r = wr * 64 + m * 16 + lr;
      ah[m] = *(const f16x8*)&S[r * 32 + sx];
      al[m] = *(const f16x8*)&S[4096 + r * 32 + sx];
    }
    #pragma unroll
    for (int n = 0; n < 2; ++n) {
      int c = wc * 32 + n * 16 + lr;
      bh[n] = *(const f16x8*)&S[8192 + c * 32 + sx];
      bl[n] = *(const f16x8*)&S[12288 + c * 32 + sx];
    }
    #pragma unroll
    for (int m = 0; m < 4; ++m)
      #pragma unroll
      for (int n = 0; n < 2; ++n) {
        acch[m][n] = MFMA16(ah[m], bh[n], acch[m][n]);
        accl[m][n] = MFMA16(ah[m], bl[n], accl[m][n]);
        accl[m][n] = MFMA16(al[m], bh[n], accl[m][n]);
      }
    __builtin_amdgcn_s_barrier();
    __builtin_amdgcn_sched_barrier(0);
    if (kc + 2 < 16) {
      #pragma unroll
      for (int j = 0; j < 4; ++j) gl16(gsrc[j] + (kc + 2) * 32, &SMb[(kc & 1) * 16384 + loff[j]]);
    }
  }
  #pragma unroll
  for (int m = 0; m < 4; ++m)
    #pragma unroll
    for (int n = 0; n < 2; ++n) {
      int col = col0 + wc * 32 + n * 16 + lr;
      float bb = (col < 512) ? bq[col] : (col < 1024) ? bk[col - 512] : bv[col - 1024];
      #pragma unroll
      for (int r = 0; r < 4; ++r) {
        int row = row0 + wr * 64 + m * 16 + lkq * 4 + r;
        float val = acch[m][n][r] + accl[m][n][r] * LO_SCALE + bb;
        f16 vh = (f16)val;
        f16 vl = (f16)((val - (float)vh) * 4096.0f);
        qkvh[(size_t)row * 1536 + col] = (u32)f16b(vh) | ((u32)f16b(vl) << 16);
      }
    }
}

__global__ __launch_bounds__(512, 2) void qkv_gemm_kernel(
    const u16* __restrict__ hh, const u16* __restrict__ hl,
    const u16* __restrict__ whi, const u16* __restrict__ wlo,
    const float* __restrict__ bq, const float* __restrict__ bk,
    const float* __restrict__ bv, u32* __restrict__ qkvh, int M0)
{
  __shared__ alignas(16) u16 SM[2][16384];
  qkv_body(blockIdx.x + 12 * blockIdx.y, &SM[0][0],
           hh, hl, whi, wlo, bq, bk, bv, qkvh, M0);
}

// ---------------------------------------------------------------------------
// wo GEMM body: clone of qkv template, M=16384 N=512 K=512, 512 blocks.
// Epilogue: dout = x + val (+bo). XCD remap: 16 row-tiles x 4 col-tiles/XCD.
__device__ __forceinline__ void wo_body(
    int lid, u16* SMb,
    const u16* __restrict__ cth, const u16* __restrict__ ctl,
    const u16* __restrict__ whi, const u16* __restrict__ wlo,
    const float* __restrict__ bo, const float* __restrict__ x,
    float* __restrict__ dout, int M0)
{
  const int tid = threadIdx.x;
  const int lane = tid & 63, w = tid >> 6;
  const int c8 = lid & 7, kk = lid >> 3;      // kk in [0,64)
  const int rt = c8 * 16 + (kk >> 2), ct = kk & 3;
  const int col0 = ct * 128;
  const int row0 = rt * 128;
  const int wr = w >> 2, wc = w & 3;
  const int lr = lane & 15, lkq = lane >> 4;
  const int sx = (lkq ^ SWZF(lr)) * 8;
  const int lrow = lane >> 2;
  const int lcs = ((lane & 3) ^ SWZF(lrow)) * 8;

  const u16* wh3 = whi + 3 * 262144;
  const u16* wl3 = wlo + 3 * 262144;

  const u16* gsrc[4];
  int loff[4];
  #pragma unroll
  for (int j = 0; j < 4; ++j) {
    const int q = w * 4 + j;
    loff[j] = q * 512;
    if (q < 8)       gsrc[j] = cth + (size_t)(row0 + q * 16 + lrow) * 512 + lcs;
    else if (q < 16) gsrc[j] = ctl + (size_t)(row0 + (q - 8) * 16 + lrow) * 512 + lcs;
    else if (q < 24) gsrc[j] = wh3 + (size_t)(col0 + (q - 16) * 16 + lrow) * 512 + lcs;
    else             gsrc[j] = wl3 + (size_t)(col0 + (q - 24) * 16 + lrow) * 512 + lcs;
  }

  f32x4 acch[4][2], accl[4][2];
  #pragma unroll
  for (int m = 0; m < 4; ++m)
    #pragma unroll
    for (int n = 0; n < 2; ++n) {
      f32x4 zz = {0.f, 0.f, 0.f, 0.f};
      acch[m][n] = zz; accl[m][n] = zz;
    }

  #pragma unroll
  for (int j = 0; j < 4; ++j) gl16(gsrc[j], &SMb[loff[j]]);
  #pragma unroll
  for (int j = 0; j < 4; ++j) gl16(gsrc[j] + 32, &SMb[16384 + loff[j]]);

  for (int kc = 0; kc < 16; ++kc) {
    if (kc == 15) asm volatile("s_waitcnt vmcnt(0)" ::: "memory");
    else          asm volatile("s_waitcnt vmcnt(4)" ::: "memory");
    __builtin_amdgcn_s_barrier();
    __builtin_amdgcn_sched_barrier(0);
    const u16* S = &SMb[(kc & 1) * 16384];
    f16x8 ah[4], al[4], bh[2], bl[2];
    #pragma unroll
    for (int m = 0; m < 4; ++m) {
      int r = wr * 64 + m * 16 + lr;
      ah[m] = *(const f16x8*)&S[r * 32 + sx];
      al[m] = *(const f16x8*)&S[4096 + r * 32 + sx];
    }
    #pragma unroll
    for (int n = 0; n < 2; ++n) {
      int c = wc * 32 + n * 16 + lr;
      bh[n] = *(const f16x8*)&S[8192 + c * 32 + sx];
      bl[n] = *(const f16x8*)&S[12288 + c * 32 + sx];
    }
    #pragma unroll
    for (int m = 0; m < 4; ++m)
      #pragma unroll
      for (int n = 0; n < 2; ++n) {
        acch[m][n] = MFMA16(ah[m], bh[n], acch[m][n]);
        accl[m][n] = MFMA16(ah[m], bl[n], accl[m][n]);
        accl[m][n] = MFMA16(al[m], bh[n], accl[m][n]);
      }
    __builtin_amdgcn_s_barrier();
    __builtin_amdgcn_sched_barrier(0);
    if (kc + 2 < 16) {
      #pragma unroll
      for (int j = 0; j < 4; ++j) gl16(gsrc[j] + (kc + 2) * 32, &SMb[(kc & 1) * 16384 + loff[j]]);
    }
  }
  #pragma unroll
  for (int m = 0; m < 4; ++m)
    #pragma unroll
    for (int n = 0; n < 2; ++n) {
      int col = col0 + wc * 32 + n * 16 + lr;
      float bvv = bo[col];
      #pragma unroll
      for (int r = 0; r < 4; ++r) {
        int row = row0 + wr * 64 + m * 16 + lkq * 4 + r;
        float val = acch[m][n][r] + accl[m][n][r] * LO_SCALE + bvv;
        size_t gi = (size_t)(M0 + row) * 512 + col;
        dout[gi] = x[gi] + val;
      }
    }
}

__global__ __launch_bounds__(512, 2) void wo_gemm_kernel(
    const u16* __restrict__ cth, const u16* __restrict__ ctl,
    const u16* __restrict__ whi, const u16* __restrict__ wlo,
    const float* __restrict__ bo, const float* __restrict__ x,
    float* __restrict__ dout, int M0)
{
  __shared__ alignas(16) u16 SM[2][16384];
  wo_body(blockIdx.x + 4 * blockIdx.y, &SM[0][0],
          cth, ctl, whi, wlo, bo, x, dout, M0);
}

// ---------------------------------------------------------------------------
// Attention only (per quarter): 32 tokens (2 seqs) per block, 8 waves.
__global__ __launch_bounds__(512) void attn_kernel(
    const u32* __restrict__ qkvh, u16* __restrict__ cth, u16* __restrict__ ctl)
{
  __shared__ alignas(16) u32 vS[16384];        // 64KB: packed V
  __shared__ float pS[8][16][17];

  const int tid = threadIdx.x;
  const int lane = tid & 63, w = tid >> 6;
  const int lr = lane & 15, lkq = lane >> 4;
  const int row0 = blockIdx.x * 32;

  #pragma unroll
  for (int i = 0; i < 8; ++i) {
    int chunk = w * 8 + i;
    const u32* src = qkvh + (size_t)(row0 + (chunk >> 1)) * 1536 + 1024 + (chunk & 1) * 256 + lane * 4;
    gl16((const u16*)src, (u16*)(vS + chunk * 256));
  }
  __syncthreads();

  const int h4 = w & 3, s = w >> 2;
  #pragma unroll
  for (int g = 0; g < 2; ++g) {
    const int h = g * 4 + h4;
    f16x8 qh[2], ql[2], kh[2], kl[2];
    #pragma unroll
    for (int dc = 0; dc < 2; ++dc) {
      const u32* qp = qkvh + (size_t)(row0 + s * 16 + lr) * 1536 + h * 64 + dc * 32 + lkq * 8;
      const u32* kp = qp + 512;
      uint4 q0 = *(const uint4*)qp, q1 = *(const uint4*)(qp + 4);
      uint4 k0 = *(const uint4*)kp, k1 = *(const uint4*)(kp + 4);
      u32 qu[8] = {q0.x, q0.y, q0.z, q0.w, q1.x, q1.y, q1.z, q1.w};
      u32 ku[8] = {k0.x, k0.y, k0.z, k0.w, k1.x, k1.y, k1.z, k1.w};
      #pragma unroll
      for (int i = 0; i < 8; ++i) {
        qh[dc][i] = b2h((u16)(qu[i] & 0xffffu)); ql[dc][i] = b2h((u16)(qu[i] >> 16));
        kh[dc][i] = b2h((u16)(ku[i] & 0xffffu)); kl[dc][i] = b2h((u16)(ku[i] >> 16));
      }
    }
    f32x4 sh = {0.f, 0.f, 0.f, 0.f}, sl = {0.f, 0.f, 0.f, 0.f};
    #pragma unroll
    for (int dc = 0; dc < 2; ++dc) {
      sh = MFMA16(qh[dc], kh[dc], sh);
      sl = MFMA16(qh[dc], kl[dc], sl);
      sl = MFMA16(ql[dc], kh[dc], sl);
    }
    float p_[4];
    #pragma unroll
    for (int r = 0; r < 4; ++r) {
      float sv = (sh[r] + sl[r] * LO_SCALE) * 0.125f;
      float mx = sv;
      #pragma unroll
      for (int off = 8; off; off >>= 1) mx = fmaxf(mx, __shfl_xor(mx, off, 16));
      float e = expf(sv - mx);
      float su = e;
      #pragma unroll
      for (int off = 8; off; off >>= 1) su += __shfl_xor(su, off, 16);
      p_[r] = e / su;
    }
    #pragma unroll
    for (int r = 0; r < 4; ++r) pS[w][lkq * 4 + r][lr] = p_[r];
    f16x8 pah, pal;
    #pragma unroll
    for (int jj = 0; jj < 8; ++jj) {
      float pv = (lkq < 2) ? pS[w][lr][lkq * 8 + jj] : 0.0f;
      f16 ph = (f16)pv;
      pah[jj] = ph;
      pal[jj] = (f16)((pv - (float)ph) * 4096.0f);
    }
    #pragma unroll
    for (int cf = 0; cf < 4; ++cf) {
      f16x8 vhf, vlf;
      #pragma unroll
      for (int jj = 0; jj < 8; ++jj) {
        u32 u = (lkq < 2) ? vS[(size_t)(s * 16 + lkq * 8 + jj) * 512 + h * 64 + cf * 16 + lr] : 0u;
        vhf[jj] = b2h((u16)(u & 0xffffu));
        vlf[jj] = b2h((u16)(u >> 16));
      }
      f32x4 ch = {0.f, 0.f, 0.f, 0.f}, cl = {0.f, 0.f, 0.f, 0.f};
      ch = MFMA16(pah, vhf, ch);
      cl = MFMA16(pah, vlf, cl);
      cl = MFMA16(pal, vhf, cl);
      #pragma unroll
      for (int r = 0; r < 4; ++r) {
        float cv = ch[r] + cl[r] * LO_SCALE;
        int row = row0 + s * 16 + lkq * 4 + r;
        int d = h * 64 + cf * 16 + lr;
        size_t gi = (size_t)row * 512 + d;
        f16 chv = (f16)cv;
        cth[gi] = f16b(chv);
        ctl[gi] = f16b((f16)((cv - (float)chv) * 4096.0f));
      }
    }
  }
}

// ---------------------------------------------------------------------------
// Router (reads dout = post-attn residual): one wave per token, no LDS.
// Also writes xn[tok] = bf16 LN2(dout[tok]) (gather fused away).
__global__ __launch_bounds__(256) void router_kernel(
    const float* __restrict__ xp, const float* __restrict__ g2,
    const float* __restrict__ b2ln, const float* __restrict__ rwt,
    const float* __restrict__ rb, float* __restrict__ stats,
    int* __restrict__ t2, u16* __restrict__ xn)
{
  const int tid = threadIdx.x;
  const int lane = tid & 63, w = tid >> 6;
  const int tok = blockIdx.x * 4 + w;
  const float* xr = xp + (size_t)tok * 512 + lane * 8;
  float4 a = *(const float4*)(xr);
  float4 b = *(const float4*)(xr + 4);
  double s1 = (double)a.x + a.y + a.z + a.w + b.x + b.y + b.z + b.w;
  double s2 = (double)a.x * a.x + (double)a.y * a.y + (double)a.z * a.z + (double)a.w * a.w
            + (double)b.x * b.x + (double)b.y * b.y + (double)b.z * b.z + (double)b.w * b.w;
  #pragma unroll
  for (int off = 32; off; off >>= 1) {
    s1 += __shfl_xor(s1, off, 64);
    s2 += __shfl_xor(s2, off, 64);
  }
  double mu = s1 * (1.0 / 512.0);
  double var = s2 * (1.0 / 512.0) - mu * mu;
  double rs = 1.0 / sqrt(var + 1e-5);
  if (lane == 0) {
    stats[tok * 2] = (float)mu;
    stats[tok * 2 + 1] = (float)rs;
  }
  float4 ga = *(const float4*)(g2 + lane * 8);
  float4 gb = *(const float4*)(g2 + lane * 8 + 4);
  float4 ca = *(const float4*)(b2ln + lane * 8);
  float4 cb = *(const float4*)(b2ln + lane * 8 + 4);
  // --- xn write: EXACT replica of old gather's f32 math (f32 mu/rs) ---
  {
    float muf = (float)mu, rsf = (float)rs;
    u16 ox[8];
    ox[0] = f2bf((a.x - muf) * rsf * ga.x + ca.x);
    ox[1] = f2bf((a.y - muf) * rsf * ga.y + ca.y);
    ox[2] = f2bf((a.z - muf) * rsf * ga.z + ca.z);
    ox[3] = f2bf((a.w - muf) * rsf * ga.w + ca.w);
    ox[4] = f2bf((b.x - muf) * rsf * gb.x + cb.x);
    ox[5] = f2bf((b.y - muf) * rsf * gb.y + cb.y);
    ox[6] = f2bf((b.z - muf) * rsf * gb.z + cb.z);
    ox[7] = f2bf((b.w - muf) * rsf * gb.w + cb.w);
    *(short8*)(xn + (size_t)tok * 512 + lane * 8) = *(const short8*)ox;
  }
  float h[8];
  h[0] = (float)(((double)a.x - mu) * rs * (double)ga.x + (double)ca.x);
  h[1] = (float)(((double)a.y - mu) * rs * (double)ga.y + (double)ca.y);
  h[2] = (float)(((double)a.z - mu) * rs * (double)ga.z + (double)ca.z);
  h[3] = (float)(((double)a.w - mu) * rs * (double)ga.w + (double)ca.w);
  h[4] = (float)(((double)b.x - mu) * rs * (double)gb.x + (double)cb.x);
  h[5] = (float)(((double)b.y - mu) * rs * (double)gb.y + (double)cb.y);
  h[6] = (float)(((double)b.z - mu) * rs * (double)gb.z + (double)cb.z);
  h[7] = (float)(((double)b.w - mu) * rs * (double)gb.w + (double)cb.w);
  double acc[8];
  #pragma unroll
  for (int e = 0; e < 8; ++e) {
    const float* wp = rwt + e * 512 + lane * 8;
    float4 w0 = *(const float4*)wp;
    float4 w1 = *(const float4*)(wp + 4);
    acc[e] = (double)h[0] * (double)w0.x + (double)h[1] * (double)w0.y
           + (double)h[2] * (double)w0.z + (double)h[3] * (double)w0.w
           + (double)h[4] * (double)w1.x + (double)h[5] * (double)w1.y
           + (double)h[6] * (double)w1.z + (double)h[7] * (double)w1.w;
  }
  #pragma unroll
  for (int e = 0; e < 8; ++e) {
    acc[e] += __shfl_xor(acc[e], 8, 64);
    acc[e] += __shfl_xor(acc[e], 16, 64);
    acc[e] += __shfl_xor(acc[e], 32, 64);
  }
  const int b0 = lane & 1, b1 = (lane >> 1) & 1, b2_ = (lane >> 2) & 1;
  double t4[4];
  #pragma unroll
  for (int k = 0; k < 4; ++k) {
    double mine = b0 ? acc[2 * k + 1] : acc[2 * k];
    double send = b0 ? acc[2 * k] : acc[2 * k + 1];
    t4[k] = mine + __shfl_xor(send, 1, 64);
  }
  double u2[2];
  #pragma unroll
  for (int k = 0; k < 2; ++k) {
    double mine = b1 ? t4[2 * k + 1] : t4[2 * k];
    double send = b1 ? t4[2 * k] : t4[2 * k + 1];
    u2[k] = mine + __shfl_xor(send, 2, 64);
  }
  {
    double mine = b2_ ? u2[1] : u2[0];
    double send = b2_ ? u2[0] : u2[1];
    double tot = mine + __shfl_xor(send, 4, 64);
    const int e = lane & 7;
    double lg = tot + (double)rb[e];
    double vv = lg; int ix = e;
    #pragma unroll
    for (int off = 4; off; off >>= 1) {
      double ov = __shfl_xor(vv, off, 8);
      int oi = __shfl_xor(ix, off, 8);
      if (ov > vv || (ov == vv && oi < ix)) { vv = ov; ix = oi; }
    }
    double v2 = (e == ix) ? -1.0e300 : lg; int ix2 = e;
    #pragma unroll
    for (int off = 4; off; off >>= 1) {
      double ov = __shfl_xor(v2, off, 8);
      int oi = __shfl_xor(ix2, off, 8);
      if (ov > v2 || (ov == v2 && oi < ix2)) { v2 = ov; ix2 = oi; }
    }
    if (lane == 0) t2[tok] = ix | (ix2 << 8);
  }
}

// ---------------------------------------------------------------------------
// Routing scans (all deterministic, zero atomics).
__global__ __launch_bounds__(256) void scan1_kernel(
    const int* __restrict__ t2, int* __restrict__ blkcnt, int* __restrict__ ranks)
{
  __shared__ u32 mask[256];
  __shared__ u16 rk[256][8];
  const int t = threadIdx.x, tok = blockIdx.x * 256 + t;
  const int p = t2[tok];
  const int e1 = p & 0xff, e2 = (p >> 8) & 0xff;
  mask[t] = (1u << e1) | (1u << e2);
  __syncthreads();
  if (t < 8) {
    int c = 0;
    for (int i = 0; i < 256; ++i) { rk[i][t] = (u16)c; c += (mask[i] >> t) & 1u; }
    blkcnt[blockIdx.x * 8 + t] = c;
  }
  __syncthreads();
  ranks[tok] = (int)rk[t][e1] | ((int)rk[t][e2] << 16);
}

__global__ void scan2_kernel(const int* __restrict__ blkcnt,
                             int* __restrict__ offs)
{
  const int e = threadIdx.x;
  if (e < 8) {
    int off = 0;
    for (int b = 0; b < 256; ++b) { offs[b * 8 + e] = off; off += blkcnt[b * 8 + e]; }
  }
}

// scan3: winner determination + per-block winner counts/ranks (scan1 pattern).
__global__ __launch_bounds__(256) void scan3_kernel(
    const int* __restrict__ t2, const int* __restrict__ ranks,
    const int* __restrict__ offs, int* __restrict__ wblkcnt,
    int* __restrict__ wrk_tok)
{
  __shared__ u32 wmask[256];
  __shared__ u16 wrk[256][8];
  const int t = threadIdx.x, blk = blockIdx.x, tok = blk * 256 + t;
  const int p = t2[tok];
  const int e1 = p & 0xff, e2 = (p >> 8) & 0xff;
  const int r = ranks[tok];
  const int s1 = offs[blk * 8 + e1] + (r & 0xffff);
  const int s2 = offs[blk * 8 + e2] + ((r >> 16) & 0xffff);
  int w = -1;
  if (s1 < CAP) w = (e1 > w) ? e1 : w;
  if (s2 < CAP) w = (e2 > w) ? e2 : w;
  wmask[t] = (w >= 0) ? (1u << w) : 0u;
  __syncthreads();
  if (t < 8) {
    int c = 0;
    for (int i = 0; i < 256; ++i) { wrk[i][t] = (u16)c; c += (wmask[i] >> t) & 1u; }
    wblkcnt[blk * 8 + t] = c;
  }
  __syncthreads();
  wrk_tok[tok] = (w >= 0) ? ((int)wrk[t][w] | (w << 16)) : -1;
}

// scan4: prefix-sum winner block counts -> per-block winner offsets + totals.
__global__ void scan4_kernel(const int* __restrict__ wblkcnt,
                             int* __restrict__ woffs, int* __restrict__ wcnt)
{
  const int e = threadIdx.x;
  if (e < 8) {
    int off = 0;
    for (int b = 0; b < 256; ++b) { woffs[b * 8 + e] = off; off += wblkcnt[b * 8 + e]; }
    wcnt[e] = off;
  }
}

// scan5: scatter winner tokens to compacted per-expert lists (deterministic).
__global__ __launch_bounds__(256) void scan5_kernel(
    const int* __restrict__ wrk_tok, const int* __restrict__ woffs,
    int* __restrict__ wlist)
{
  const int t = threadIdx.x, blk = blockIdx.x, tok = blk * 256 + t;
  const int pr = wrk_tok[tok];
  if (pr >= 0) {
    const int w = pr >> 16, rk = pr & 0xffff;
    wlist[w * CAPP + woffs[blk * 8 + w] + rk] = tok;
  }
}

// ---------------------------------------------------------------------------
// FFN GEMM body, 8-WAVE variant (R18 best-measured config): tile 128 rows x
// 256 cols, triple-ring + single barrier + counted vmcnt; 512 threads /
// 8 waves (2x4), wave owns 64x64 (acc 4x4), staging 3 gl16/thread
// (vmcnt(3), drain 0 at tail). 72KB LDS -> 2 blocks/CU -> 16 waves/CU.
// TLP map (R10->R20): 8 w/CU=146us, 16 w/CU=137us (this), 2-ring@48KB
// +extra barrier=140us, forced 3blk/CU spills. This is the optimum.
// XCD remap: round-robin row-tile -> XCD (wy = (pr%13)*8 + c8). Padded
// wy==103 exits; tiles beyond the expert's winner count exit (pre-barrier).
// EPI 0 (ffn1): A = xn with per-lane winner-token indirection; GELU -> hid.
// EPI 1 (ffn2): scatter += val into dout for all rows < wcnt (all winners).
template<int EPI, int NKC, int AST, int BST, int NX>
__device__ __forceinline__ void ffn_body(
    int lid, u16* SMb,
    const u16* __restrict__ A, const u16* __restrict__ Bw,
    const float* __restrict__ bias, u16* __restrict__ outb,
    const int* __restrict__ list, const int* __restrict__ cnts,
    float* __restrict__ dout, int ebase)
{
  const int c8 = lid & 7;
  const int kk = lid >> 3;              // [0, NX*26)
  const int wx = kk & (NX - 1);
  const int pr = kk / NX;               // [0, 26)
  const int wz = pr / 13;
  const int wy = (pr % 13) * 8 + c8;    // round-robin row-tile -> XCD
  if (wy >= 103) return;                // padded tile (uniform exit, pre-barrier)
  const int ez = wz;
  const int expert = ebase + ez;
  const int cnt = cnts[expert];
  const int row0 = wy * 128;
  if (row0 >= cnt) return;              // winner-compacted tail (uniform exit)
  const int tid = threadIdx.x;
  const int lane = tid & 63, w = tid >> 6;   // 8 waves
  const int wr = w >> 2, wc = w & 3;         // wave tile: 64 rows x 64 cols
  const int colb = wx * 256;
  const int lr = lane & 15, lkq = lane >> 4;
  const int sx = (lkq ^ SWZF(lr)) * 8;
  const int lrow = lane >> 2;
  const int lcs = ((lane & 3) ^ SWZF(lrow)) * 8;

  const u16* Bp = Bw + (size_t)expert * 1048576;

  // staging: 24 chunks (A 8 + B 16) over 8 waves = 3 chunks/wave
  const u16* gsrc[3];
  int loff[3];
  #pragma unroll
  for (int j = 0; j < 3; ++j) {
    const int c = w * 3 + j;             // 0..23 (wave-uniform)
    if (c < 8) {
      const int q = c;
      int arow = row0 + q * 16 + lrow;
      if (EPI == 0) {
        int tok = list[(size_t)expert * CAPP + arow] & 65535;
        gsrc[j] = A + (size_t)tok * 512 + lcs;
      } else {
        gsrc[j] = A + (size_t)ez * CAPP * 2048 + (size_t)arow * AST + lcs;
      }
      loff[j] = q * 512;
    } else {
      const int q = c - 8;
      gsrc[j] = Bp + (size_t)(colb + q * 16 + lrow) * BST + lcs;
      loff[j] = 4096 + q * 512;
    }
  }

  f32x4 acc[4][4];
  #pragma unroll
  for (int m = 0; m < 4; ++m)
    #pragma unroll
    for (int n = 0; n < 4; ++n) {
      f32x4 zz = {0.f, 0.f, 0.f, 0.f};
      acc[m][n] = zz;
    }

  #pragma unroll
  for (int j = 0; j < 3; ++j) gl16(gsrc[j], &SMb[loff[j]]);
  #pragma unroll
  for (int j = 0; j < 3; ++j) gl16(gsrc[j] + 32, &SMb[12288 + loff[j]]);

  int cur = 0, nx2 = 2;   // buffer indices: kc%3 and (kc+2)%3
  for (int kc = 0; kc < NKC; ++kc) {
    if (kc == NKC - 1) asm volatile("s_waitcnt vmcnt(0)" ::: "memory");
    else               asm volatile("s_waitcnt vmcnt(3)" ::: "memory");
    __builtin_amdgcn_s_barrier();
    __builtin_amdgcn_sched_barrier(0);
    if (kc + 2 < NKC) {
      #pragma unroll
      for (int j = 0; j < 3; ++j) gl16(gsrc[j] + (kc + 2) * 32, &SMb[nx2 * 12288 + loff[j]]);
    }
    const u16* S = &SMb[cur * 12288];
    short8 af[4], bf[4];
    #pragma unroll
    for (int m = 0; m < 4; ++m)
      af[m] = *(const short8*)&S[(wr * 64 + m * 16 + lr) * 32 + sx];
    #pragma unroll
    for (int n = 0; n < 4; ++n)
      bf[n] = *(const short8*)&S[4096 + (wc * 64 + n * 16 + lr) * 32 + sx];
    #pragma unroll
    for (int m = 0; m < 4; ++m)
      #pragma unroll
      for (int n = 0; n < 4; ++n)
        acc[m][n] = MFMAB(af[m], bf[n], acc[m][n]);
    cur = (cur == 2) ? 0 : cur + 1;
    nx2 = (nx2 == 2) ? 0 : nx2 + 1;
  }

  if (EPI == 0) {
    #pragma unroll
    for (int m = 0; m < 4; ++m)
      #pragma unroll
      for (int n = 0; n < 4; ++n) {
        int col = colb + wc * 64 + n * 16 + lr;
        float bvv = bias[expert * 2048 + col];
        #pragma unroll
        for (int r = 0; r < 4; ++r) {
          int row = row0 + wr * 64 + m * 16 + lkq * 4 + r;
          float val = acc[m][n][r] + bvv;
          outb[(size_t)ez * CAPP * 2048 + (size_t)row * 2048 + col] = f2bf(gelu_f(val));
        }
      }
  } else {
    const int* gidx = list + (size_t)expert * CAPP;
    #pragma unroll
    for (int m = 0; m < 4; ++m) {
      int rowb = row0 + wr * 64 + m * 16 + lkq * 4;
      #pragma unroll
      for (int r = 0; r < 4; ++r) {
        int row = rowb + r;
        if (row < cnt) {
          int tok = gidx[row];
          #pragma unroll
          for (int n = 0; n < 4; ++n) {
            int col = colb + wc * 64 + n * 16 + lr;
            float val = acc[m][n][r] + bias[expert * 512 + col];
            size_t oi = (size_t)tok * 512 + col;
            dout[oi] = dout[oi] + val;   // dout holds x2; same-thread RMW
          }
        }
      }
    }
  }
}

// Merged dispatch: role-2 (ffn2 of previous expert pair, long 64-step blocks)
// occupies bx < nb2 so it launches FIRST; role-1 (ffn1 of current pair) fills
// the remaining CU slots around it.
__global__ __launch_bounds__(512, 4) void ffn_merged_kernel(
    const u16* __restrict__ xn, const u16* __restrict__ w1t,
    const float* __restrict__ b1, u16* __restrict__ hidW,
    const u16* __restrict__ hidR, const u16* __restrict__ w2t,
    const float* __restrict__ b2,
    const int* __restrict__ wlist, const int* __restrict__ wcnt,
    float* __restrict__ dout, int nb2, int eb1, int eb2)
{
  __shared__ alignas(16) u16 SM[3][12288];   // 72KB -> 2 blocks/CU (16 waves)
  const int bx = blockIdx.x;
  if (bx < nb2) {
    ffn_body<1, 64, 2048, 2048, 2>(bx, &SM[0][0], hidR, w2t, b2, nullptr,
                                   wlist, wcnt, dout, eb2);
  } else {
    ffn_body<0, 16, 512, 512, 8>(bx - nb2, &SM[0][0], xn, w1t, b1, hidW,
                                 wlist, wcnt, nullptr, eb1);
  }
}

// ---------------------------------------------------------------------------
extern "C" void kernel_launch(void* const* d_in, const int* in_sizes, int n_in,
                              void* d_out, int out_size, void* d_ws, size_t ws_size,
                              hipStream_t stream) {
  const float* x    = (const float*)d_in[0];
  const float* ln1g = (const float*)d_in[1];
  const float* ln1b = (const float*)d_in[2];
  const float* ln2g = (const float*)d_in[3];
  const float* ln2b = (const float*)d_in[4];
  const float* wq   = (const float*)d_in[5];
  const float* bq   = (const float*)d_in[6];
  const float* wk   = (const float*)d_in[7];
  const float* bk   = (const float*)d_in[8];
  const float* wv   = (const float*)d_in[9];
  const float* bv   = (const float*)d_in[10];
  const float* wo   = (const float*)d_in[11];
  const float* bo   = (const float*)d_in[12];
  const float* rw   = (const float*)d_in[13];
  const float* rb   = (const float*)d_in[14];
  const float* w1   = (const float*)d_in[15];
  const float* b1   = (const float*)d_in[16];
  const float* w2   = (const float*)d_in[17];
  const float* b2   = (const float*)d_in[18];
  float* dout = (float*)d_out;

  char* ws = (char*)d_ws;
  u16*   hh   = (u16*)(ws + 0LL);            // [65536][512] f16 hi
  u16*   hl   = (u16*)(ws + 67108864LL);     // lo plane
  u32*   qkvh = (u32*)(ws + 134217728LL);    // [16384][1536] packed quarter
  u16*   cth  = (u16*)(ws + 234881024LL);    // ctx hi quarter (dead before router)
  u16*   ctl  = (u16*)(ws + 251658240LL);    // ctx lo quarter
  u16*   whi  = (u16*)(ws + 369098752LL);
  u16*   wlo  = (u16*)(ws + 371195904LL);
  float* rwt  = (float*)(ws + 373293056LL);
  float* st2  = (float*)(ws + 373309440LL);
  int*   t2   = (int*)(ws + 373833728LL);
  int*   rks  = (int*)(ws + 374095872LL);
  int*   bc   = (int*)(ws + 374358016LL);
  int*   offs = (int*)(ws + 374366208LL);
  int*   wcnt = (int*)(ws + 374374400LL);    // 8 winner counts
  int*   wlst = (int*)(ws + 374374464LL);    // [8][CAPP] winner token lists
  int*   wrkt = (int*)(ws + 374796352LL);    // [65536] packed (winner, rank)
  int*   wbc  = (int*)(ws + 375058496LL);    // [256][8] winner block counts
  int*   wofs = (int*)(ws + 375066688LL);    // [256][8] winner block offsets
  // aliases (regions dead by the time these are written)
  u16*   w1t  = (u16*)(ws + 0LL);            // in hh (dead after qkv q3)
  u16*   w2t  = (u16*)(ws + 16777216LL);     // in hh
  u16*   xn   = (u16*)(ws + 33554432LL);     // [65536][512] bf16 (32..96MB; hh/hl dead)
  u16*   hid0 = (u16*)(ws + 100663296LL);    // 2 experts x CAPP x 2048 bf16 (103MB)
  u16*   hid1 = (u16*)(ws + 208666624LL);    // second buffer (ends ~302MB < whi)

  prep1_kernel<<<dim3(1024, 1, 5), 256, 0, stream>>>(wq, wk, wv, wo, rw, whi, wlo, rwt);
  ln1_kernel<<<16384, 256, 0, stream>>>(x, ln1g, ln1b, hh, hl);
  for (int q = 0; q < 4; ++q) {
    qkv_gemm_kernel<<<dim3(12, 128), 512, 0, stream>>>(
        hh, hl, whi, wlo, bq, bk, bv, qkvh, q * QTOK);
    attn_kernel<<<512, 512, 0, stream>>>(qkvh, cth, ctl);
    wo_gemm_kernel<<<dim3(4, 128), 512, 0, stream>>>(
        cth, ctl, whi, wlo, bo, x, dout, q * QTOK);
  }
  prep2_kernel<<<dim3(256, 1, 16), 256, 0, stream>>>(w1, w2, w1t, w2t);
  router_kernel<<<16384, 256, 0, stream>>>(dout, ln2g, ln2b, rwt, rb, st2, t2, xn);
  scan1_kernel<<<256, 256, 0, stream>>>(t2, bc, rks);
  scan2_kernel<<<1, 256, 0, stream>>>(bc, offs);
  scan3_kernel<<<256, 256, 0, stream>>>(t2, rks, offs, wbc, wrkt);
  scan4_kernel<<<1, 256, 0, stream>>>(wbc, wofs, wcnt);
  scan5_kernel<<<256, 256, 0, stream>>>(wrkt, wofs, wlst);
  // 5-stage software pipeline: stage s runs ffn1(experts 2s,2s+1) into
  // hid[s&1] concurrently with ffn2(experts 2s-2,2s-1) from hid[(s-1)&1].
  // Winner-compacted: tiles beyond each expert's winner count early-exit;
  // round-robin row-tile->XCD mapping keeps the active prefix balanced.
  // 8-wave blocks (512 thr): 16 waves/CU at the same tile/schedule.
  for (int s = 0; s < 5; ++s) {
    const int nb1 = (s < 4) ? 1664 : 0;   // 8*104*2 (incl. padded tiles)
    const int nb2 = (s > 0) ? 416 : 0;    // 2*104*2
    u16* hw = (s & 1) ? hid1 : hid0;
    const u16* hr = ((s - 1) & 1) ? hid1 : hid0;
    ffn_merged_kernel<<<nb1 + nb2, 512, 0, stream>>>(
        xn, w1t, b1, hw, hr, w2t, b2, wlst, wcnt, dout,
        nb2, s * 2, (s - 1) * 2);
  }
}